// Round 7
// baseline (1220.312 us; speedup 1.0000x reference)
//
#include <hip/hip_runtime.h>
#include <hip/hip_bf16.h>
#include <math.h>

typedef __hip_bfloat16 bf16;
typedef short bf16x8 __attribute__((ext_vector_type(8)));
typedef float f32x4 __attribute__((ext_vector_type(4)));

static constexpr int HWPX = 16384;   // 128*128
static constexpr int NBL  = 16;      // blocks per LSTM layer (32 gates each)

__device__ inline float sigmoidf_(float x) { return 1.0f / (1.0f + expf(-x)); }
__device__ inline float bflo(unsigned u) { return __uint_as_float(u << 16); }
__device__ inline float bfhi(unsigned u) { return __uint_as_float(u & 0xffff0000u); }
__device__ inline int swz(int x) { return (x ^ (x >> 2)) & 3; }

// async global->LDS, 16B per lane; lds base wave-uniform (lane i -> +i*16)
__device__ inline void gll16(const bf16* g, short* l) {
    __builtin_amdgcn_global_load_lds(
        (const __attribute__((address_space(1))) void*)g,
        (__attribute__((address_space(3))) void*)l, 16, 0, 0);
}

// ---- p2p sync (round-7 fix): polls must be RMWs ---------------------------
// R3-R6 lesson: relaxed agent atomic LOADS of a hot flag are serviced from
// the consumer's own (stale, never-invalidated) L2; progress only on line
// eviction (~20us = L2 churn time). Atomic RMWs always execute at the LLC
// coherence point with zero cache-maintenance. fetch_max(p,-1) is a no-op
// write that LLVM does NOT fold to a load (fetch_add(p,0) would be folded).
__device__ inline int flag_poll(int* p) {
    return __hip_atomic_fetch_max(p, -1, __ATOMIC_RELAXED, __HIP_MEMORY_SCOPE_AGENT);
}
__device__ inline void flag_post(int* p) {
    __hip_atomic_fetch_add(p, 1, __ATOMIC_RELAXED, __HIP_MEMORY_SCOPE_AGENT);
}
__device__ inline unsigned long long devload2(const float* p) {
    return __hip_atomic_load((const unsigned long long*)p,
                             __ATOMIC_RELAXED, __HIP_MEMORY_SCOPE_AGENT);
}
__device__ inline void devstore(float* p, float v) {
    __hip_atomic_store(p, v, __ATOMIC_RELAXED, __HIP_MEMORY_SCOPE_AGENT);
}

// ---------------- prep: LSTM weights -> bf16 (wih0 padded 70->72) -----------
__global__ __launch_bounds__(256) void prep_lstm_k(
    const float* __restrict__ wih0, const float* __restrict__ whh0,
    const float* __restrict__ wihr, const float* __restrict__ whhr,
    bf16* __restrict__ d0, bf16* __restrict__ d1,
    bf16* __restrict__ d2, bf16* __restrict__ d3)
{
    const size_t nA = 2048ull * 72, nB = 2048ull * 512;
    const size_t nC = 5ull * 2048 * 576, nD = 5ull * 2048 * 512;
    for (size_t i = blockIdx.x * 256ull + threadIdx.x; i < nA + nB + nC + nD;
         i += (size_t)gridDim.x * 256) {
        if (i < nA) {
            int c = (int)(i % 72), r = (int)(i / 72);
            d0[i] = __float2bfloat16(c < 70 ? wih0[(size_t)r * 70 + c] : 0.f);
        } else if (i < nA + nB) {
            size_t k = i - nA; d1[k] = __float2bfloat16(whh0[k]);
        } else if (i < nA + nB + nC) {
            size_t k = i - nA - nB; d2[k] = __float2bfloat16(wihr[k]);
        } else {
            size_t k = i - nA - nB - nC; d3[k] = __float2bfloat16(whhr[k]);
        }
    }
}

// ---------------- prep: conv weights, both cams -----------------------------
struct ConvW {
    const float* src[8];
    bf16* dst[8];
};

__global__ __launch_bounds__(256) void prep_conv_k(ConvW a)
{
    const int sizes[4] = {3072, 18432, 73728, 18432};
    const int cins[4] = {3, 32, 64, 128};
    const int couts[4] = {32, 64, 128, 16};
    int total = 2 * 113664;
    for (int idx = blockIdx.x * 256 + threadIdx.x; idx < total; idx += gridDim.x * 256) {
        int i = idx, cam = 0;
        if (i >= 113664) { cam = 1; i -= 113664; }
        int layer = 0;
        while (layer < 3 && i >= sizes[layer]) { i -= sizes[layer]; ++layer; }
        const float* w = a.src[cam * 4 + layer];
        bf16* d = a.dst[cam * 4 + layer];
        if (layer == 0) {
            // [3ky][32co][32k], k = kx*8 + c
            int k = i & 31, co = (i >> 5) & 31, ky = i >> 10;
            int kx = k >> 3, c = k & 7;
            float v = (kx < 3 && c < 3) ? w[((co * 3 + c) * 3 + ky) * 3 + kx] : 0.f;
            d[i] = __float2bfloat16(v);
        } else {
            // dst [tap][kc][q][co][8]
            int CIN = cins[layer], COUT = couts[layer], KC = CIN / 32;
            int e = i & 7;
            int t2 = i >> 3;
            int co = t2 % COUT;
            int t3 = t2 / COUT;
            int q = t3 & 3;
            int t4 = t3 >> 2;
            int kc = t4 % KC;
            int tap = t4 / KC;
            d[i] = __float2bfloat16(w[((size_t)(co * CIN + kc * 32 + q * 8 + e)) * 9 + tap]);
        }
    }
}

// ---------------- conv L0: fp32 NCHW in, NHWC-32 out, cam-folded ------------
__global__ __launch_bounds__(256) void conv0_nhwc(
    const float* __restrict__ srcm, const float* __restrict__ srcs,
    const bf16* __restrict__ w0m, const bf16* __restrict__ w0s,
    const float* __restrict__ bm, const float* __restrict__ bs,
    bf16* __restrict__ out, int c0)
{
    const int y = blockIdx.x;
    const int cam = blockIdx.y;
    const int img = blockIdx.z;
    const int ci_ = cam * gridDim.z + img;
    const float* inImg = (cam ? srcs : srcm) + (size_t)(c0 + img) * 3 * HWPX;
    const bf16* wT0 = cam ? w0s : w0m;
    const float* bias = cam ? bs : bm;
    const int tid = threadIdx.x;
    const int wave = tid >> 6, lane = tid & 63;
    const int wm = wave & 1, wn = wave >> 1;
    const int q = lane >> 4, n16 = lane & 15;

    __shared__ short smem[3 * 130 * 16];

    for (int d = tid; d < 3 * 130; d += 256) {
        int x = d % 130, r = d / 130;
        int yy = y + r - 1, xx = x - 1;
        bf16 v8[8];
#pragma unroll
        for (int c = 0; c < 8; ++c) v8[c] = __float2bfloat16(0.f);
        if ((unsigned)yy < 128u && (unsigned)xx < 128u) {
            int o = yy * 128 + xx;
            v8[0] = __float2bfloat16(inImg[o]);
            v8[1] = __float2bfloat16(inImg[HWPX + o]);
            v8[2] = __float2bfloat16(inImg[2 * HWPX + o]);
        }
        *(bf16x8*)(void*)&smem[(r * 130 + x) * 16] = *(bf16x8*)(void*)v8;
        *(bf16x8*)(void*)&smem[(r * 130 + x) * 16 + 8] = (bf16x8)0;
    }
    __syncthreads();

    f32x4 acc[4];
#pragma unroll
    for (int nt = 0; nt < 4; ++nt) acc[nt] = f32x4{0.f, 0.f, 0.f, 0.f};

    const int co = wm * 16 + n16;
#pragma unroll
    for (int ky = 0; ky < 3; ++ky) {
        bf16x8 aF = *(const bf16x8*)(const void*)(wT0 + ((size_t)(ky * 32 + co) * 32) + q * 8);
#pragma unroll
        for (int nt = 0; nt < 4; ++nt) {
            int x = (wn * 4 + nt) * 16 + n16;
            int off = (q < 3) ? (ky * 130 + x + q) * 16 : (ky * 130 + x) * 16 + 8;
            bf16x8 bF = *(const bf16x8*)(const void*)&smem[off];
            acc[nt] = __builtin_amdgcn_mfma_f32_16x16x32_bf16(aF, bF, acc[nt], 0, 0, 0);
        }
    }

    int co0 = wm * 16 + q * 4;
#pragma unroll
    for (int nt = 0; nt < 4; ++nt) {
        int x = (wn * 4 + nt) * 16 + n16;
        bf16 tmp[4];
#pragma unroll
        for (int r = 0; r < 4; ++r) {
            float v = acc[nt][r] + bias[co0 + r];
            tmp[r] = __float2bfloat16(v > 0.f ? v : 0.f);
        }
        *reinterpret_cast<uint2*>(out + ((size_t)ci_ * HWPX + y * 128 + x) * 32 + co0)
            = *reinterpret_cast<uint2*>(tmp);
    }
}

// ---------------- mid convs: 2 rows x 64px per block, gll dbuf --------------
template <int CIN, int COUT>
__global__ __launch_bounds__(256, 4) void conv2r(
    const bf16* __restrict__ in, const bf16* __restrict__ wTm,
    const bf16* __restrict__ wTs, const float* __restrict__ bm,
    const float* __restrict__ bs, bf16* __restrict__ out,
    const char* __restrict__ zpage)
{
    constexpr int KC = CIN / 32;
    constexpr int NB = (KC > 1) ? 2 : 1;
    constexpr int MW = COUT / 32;       // co tiles per wave (2 co-halves)
    constexpr int SLOTS = 4 * 264;      // 4 rows x 66 x x 4 granules

    const int y0 = (blockIdx.x >> 1) * 2;
    const int x0 = (blockIdx.x & 1) * 64;
    const int cam = blockIdx.y;
    const int img = blockIdx.z;
    const int ci_ = cam * gridDim.z + img;
    const bf16* wT = cam ? wTs : wTm;
    const float* bias = cam ? bs : bm;
    const int tid = threadIdx.x;
    const int wave = tid >> 6, lane = tid & 63;
    const int wrow = wave >> 1, wm = wave & 1;
    const int q = lane >> 4, n16 = lane & 15;

    __shared__ short smem[NB][SLOTS * 8];
    const bf16* inImg = in + (size_t)ci_ * HWPX * CIN;

    const bf16* sptr[5];
#pragma unroll
    for (int it = 0; it < 5; ++it) {
        int s = it * 256 + tid;
        int r = s / 264, s2 = s - r * 264;
        int sx = s2 >> 2;
        int g = (s2 & 3) ^ swz(sx);
        int yy = y0 + r - 1, xx = x0 + sx - 1;
        bool ok = (s < SLOTS) && ((unsigned)yy < 128u) && ((unsigned)xx < 128u);
        sptr[it] = ok ? inImg + ((size_t)yy * 128 + xx) * CIN + g * 8
                      : (const bf16*)(zpage + (tid & 255) * 16);
    }
    auto stage = [&](int kc, int buf) {
#pragma unroll
        for (int it = 0; it < 5; ++it) {
            if (it * 256 + tid < SLOTS)
                gll16(sptr[it] + kc * 32, &smem[buf][it * 2048 + wave * 512]);
        }
    };

    f32x4 acc[MW][4];
#pragma unroll
    for (int mt = 0; mt < MW; ++mt)
#pragma unroll
        for (int nt = 0; nt < 4; ++nt) acc[mt][nt] = f32x4{0.f, 0.f, 0.f, 0.f};

    stage(0, 0);
    for (int kc = 0; kc < KC; ++kc) {
        __syncthreads();
        if (kc + 1 < KC) stage(kc + 1, (kc + 1) % NB);
        const short* sb = smem[kc % NB];
#pragma unroll
        for (int ky = 0; ky < 3; ++ky) {
#pragma unroll
            for (int kx = 0; kx < 3; ++kx) {
                bf16x8 aF[MW];
#pragma unroll
                for (int mt = 0; mt < MW; ++mt) {
                    int co = (wm * MW + mt) * 16 + n16;
                    aF[mt] = *(const bf16x8*)(const void*)(wT +
                        ((((size_t)(ky * 3 + kx) * KC + kc) * 4 + q) * COUT + co) * 8);
                }
#pragma unroll
                for (int nt = 0; nt < 4; ++nt) {
                    int xt = nt * 16 + n16 + kx;           // 0..65
                    int slot = (wrow + ky) * 264 + xt * 4 + (q ^ swz(xt));
                    bf16x8 bF = *(const bf16x8*)(const void*)&sb[slot * 8];
#pragma unroll
                    for (int mt = 0; mt < MW; ++mt)
                        acc[mt][nt] = __builtin_amdgcn_mfma_f32_16x16x32_bf16(
                            aF[mt], bF, acc[mt][nt], 0, 0, 0);
                }
            }
        }
    }

    const int y = y0 + wrow;
#pragma unroll
    for (int mt = 0; mt < MW; ++mt) {
        int co0 = (wm * MW + mt) * 16 + q * 4;
#pragma unroll
        for (int nt = 0; nt < 4; ++nt) {
            int x = x0 + nt * 16 + n16;
            bf16 tmp[4];
#pragma unroll
            for (int r = 0; r < 4; ++r) {
                float v = acc[mt][nt][r] + bias[co0 + r];
                tmp[r] = __float2bfloat16(v > 0.f ? v : 0.f);
            }
            *reinterpret_cast<uint2*>(out + ((size_t)ci_ * HWPX + y * 128 + x) * COUT + co0)
                = *reinterpret_cast<uint2*>(tmp);
        }
    }
}

// ---------------- conv4 (128->16): half-row x-split + softmax partials ------
__global__ __launch_bounds__(256, 6) void conv4_xs(
    const bf16* __restrict__ in, const bf16* __restrict__ wTm,
    const bf16* __restrict__ wTs, const float* __restrict__ bm,
    const float* __restrict__ bs,
    float* __restrict__ partial,   // [gimg][16][256] x {M,S,SX,-}
    const char* __restrict__ zpage, int c0)
{
    constexpr int CIN = 128, COUT = 16, KC = 4;
    constexpr int SLOTS = 3 * 66 * 4;
    const int y = blockIdx.x >> 1;
    const int xh = blockIdx.x & 1;
    const int x0 = xh * 64;
    const int cam = blockIdx.y;
    const int img = blockIdx.z;
    const int ci_ = cam * gridDim.z + img;
    const int gimg = cam * 40 + c0 + img;
    const bf16* wT = cam ? wTs : wTm;
    const float* bias = cam ? bs : bm;
    const int tid = threadIdx.x;
    const int wave = tid >> 6, lane = tid & 63;
    const int q = lane >> 4, n16 = lane & 15;

    __shared__ short smem[2][SLOTS * 8];
    __shared__ float sred[3][4][16];
    const bf16* inImg = in + (size_t)ci_ * HWPX * CIN;

    const bf16* sptr[4];
#pragma unroll
    for (int it = 0; it < 4; ++it) {
        int s = it * 256 + tid;
        int r = s / 264, s2 = s - r * 264;
        int sx = s2 >> 2;
        int g = (s2 & 3) ^ swz(sx);
        int yy = y + r - 1, xx = x0 + sx - 1;
        bool ok = (s < SLOTS) && ((unsigned)yy < 128u) && ((unsigned)xx < 128u);
        sptr[it] = ok ? inImg + ((size_t)yy * 128 + xx) * CIN + g * 8
                      : (const bf16*)(zpage + (tid & 255) * 16);
    }
    auto stage = [&](int kc, int buf) {
#pragma unroll
        for (int it = 0; it < 4; ++it) {
            if (it * 256 + tid < SLOTS)
                gll16(sptr[it] + kc * 32, &smem[buf][it * 2048 + wave * 512]);
        }
    };

    f32x4 acc = f32x4{0.f, 0.f, 0.f, 0.f};

    stage(0, 0);
    for (int kc = 0; kc < KC; ++kc) {
        __syncthreads();
        if (kc + 1 < KC) stage(kc + 1, (kc + 1) & 1);
        const short* sb = smem[kc & 1];
#pragma unroll
        for (int ky = 0; ky < 3; ++ky) {
#pragma unroll
            for (int kx = 0; kx < 3; ++kx) {
                bf16x8 aF = *(const bf16x8*)(const void*)(wT +
                    ((((size_t)(ky * 3 + kx) * KC + kc) * 4 + q) * COUT + n16) * 8);
                int xt = wave * 16 + n16 + kx;
                int slot = xt * 4 + (q ^ swz(xt));
                bf16x8 bF = *(const bf16x8*)(const void*)&sb[ky * 2112 + slot * 8];
                acc = __builtin_amdgcn_mfma_f32_16x16x32_bf16(aF, bF, acc, 0, 0, 0);
            }
        }
    }

    // bias + relu; online partials over this 64px half-row (co = q*4+r)
    float v[4];
    int x = x0 + wave * 16 + n16;
    float px = -1.f + (2.f / 127.f) * x;
#pragma unroll
    for (int r = 0; r < 4; ++r) {
        float t = acc[r] + bias[q * 4 + r];
        v[r] = t > 0.f ? t : 0.f;
    }
    float M[4];
#pragma unroll
    for (int r = 0; r < 4; ++r) {
        M[r] = v[r];
        M[r] = fmaxf(M[r], __shfl_xor(M[r], 1));
        M[r] = fmaxf(M[r], __shfl_xor(M[r], 2));
        M[r] = fmaxf(M[r], __shfl_xor(M[r], 4));
        M[r] = fmaxf(M[r], __shfl_xor(M[r], 8));
    }
    if (n16 == 0)
#pragma unroll
        for (int r = 0; r < 4; ++r) sred[0][wave][q * 4 + r] = M[r];
    __syncthreads();
#pragma unroll
    for (int r = 0; r < 4; ++r) {
        M[r] = fmaxf(fmaxf(sred[0][0][q * 4 + r], sred[0][1][q * 4 + r]),
                     fmaxf(sred[0][2][q * 4 + r], sred[0][3][q * 4 + r]));
    }
    float s[4], sx[4];
#pragma unroll
    for (int r = 0; r < 4; ++r) {
        float e = expf(v[r] - M[r]);
        s[r] = e; sx[r] = e * px;
        s[r] += __shfl_xor(s[r], 1);  sx[r] += __shfl_xor(sx[r], 1);
        s[r] += __shfl_xor(s[r], 2);  sx[r] += __shfl_xor(sx[r], 2);
        s[r] += __shfl_xor(s[r], 4);  sx[r] += __shfl_xor(sx[r], 4);
        s[r] += __shfl_xor(s[r], 8);  sx[r] += __shfl_xor(sx[r], 8);
    }
    __syncthreads();
    if (n16 == 0)
#pragma unroll
        for (int r = 0; r < 4; ++r) {
            sred[1][wave][q * 4 + r] = s[r];
            sred[2][wave][q * 4 + r] = sx[r];
        }
    __syncthreads();
    if (tid < 16) {
        float S = sred[1][0][tid] + sred[1][1][tid] + sred[1][2][tid] + sred[1][3][tid];
        float SX = sred[2][0][tid] + sred[2][1][tid] + sred[2][2][tid] + sred[2][3][tid];
        float Mv = fmaxf(fmaxf(sred[0][0][tid], sred[0][1][tid]),
                         fmaxf(sred[0][2][tid], sred[0][3][tid]));
        float* pp = partial + (((size_t)gimg * 16 + tid) * 256 + (y * 2 + xh)) * 4;
        pp[0] = Mv; pp[1] = S; pp[2] = SX;
    }
}

// ---------------- merge partials -> (ex, ey), both cams ---------------------
__global__ __launch_bounds__(256) void ssmerge_k(
    const float* __restrict__ partial, float* __restrict__ featm,
    float* __restrict__ feats)
{
    const int img = blockIdx.x;          // 0..79
    const int cam = img / 40, li = img % 40;
    float* feat = cam ? feats : featm;
    const int tid = threadIdx.x;
    const int co = tid >> 4, s = tid & 15;
    const float* base = partial + ((size_t)img * 16 + co) * 256 * 4;
    float M = -1e30f, S = 0.f, SX = 0.f, SY = 0.f;
    for (int i = s; i < 256; i += 16) {
        float m = base[i * 4], sv = base[i * 4 + 1], sxv = base[i * 4 + 2];
        float py = -1.f + (2.f / 127.f) * (i >> 1);
        float Mn = fmaxf(M, m);
        float w0 = expf(M - Mn), w1 = expf(m - Mn);
        S = S * w0 + sv * w1;
        SX = SX * w0 + sxv * w1;
        SY = SY * w0 + sv * py * w1;
        M = Mn;
    }
#pragma unroll
    for (int mask = 1; mask < 16; mask <<= 1) {
        float Mo = __shfl_xor(M, mask), So = __shfl_xor(S, mask);
        float SXo = __shfl_xor(SX, mask), SYo = __shfl_xor(SY, mask);
        float Mn = fmaxf(M, Mo);
        float w0 = expf(M - Mn), w1 = expf(Mo - Mn);
        S = S * w0 + So * w1; SX = SX * w0 + SXo * w1; SY = SY * w0 + SYo * w1;
        M = Mn;
    }
    if (s == 0) {
        feat[(size_t)li * 32 + 2 * co] = SX / S;
        feat[(size_t)li * 32 + 2 * co + 1] = SY / S;
    }
}

// ---------------- LSTM helpers ----------------------------------------------
__device__ inline float imgfeat(const float* featm, const float* feats,
                                int b, int t, int k)
{
    int idx = (b * 10 + t) * 32;
    return k < 32 ? featm[idx + k] : feats[idx + k - 32];
}

// per-thread GEMV slice: 32-gate block, all 4 batches folded into the thread.
// NB1 = K1/8 (compile-time) -> fully unrolled, pipelined weight loads.
// (verified correct in rounds 5 and 6)
template <int NB1>
__device__ inline void cell_mm(const bf16* __restrict__ wih,
                               const bf16* __restrict__ whh,
                               const float* __restrict__ xs0,
                               int j, int sub, float (&dg)[4][4])
{
    constexpr int K1 = NB1 * 8;
    constexpr int XS = K1 + 512;
#pragma unroll
    for (int r = 0; r < 4; ++r) {
        const uint4* __restrict__ w1 =
            reinterpret_cast<const uint4*>(wih + (size_t)(j + r * 512) * K1);
#pragma unroll
        for (int g0 = 0; g0 < NB1; g0 += 8) {
            int g = g0 + sub;
            if (g0 + 7 < NB1 || g < NB1) {      // compile-time shaped predicate
                uint4 u = w1[g];
                float a0 = bflo(u.x), a1 = bfhi(u.x), a2 = bflo(u.y), a3 = bfhi(u.y);
                float a4 = bflo(u.z), a5 = bfhi(u.z), a6 = bflo(u.w), a7 = bfhi(u.w);
#pragma unroll
                for (int b = 0; b < 4; ++b) {
                    const float* xp = xs0 + b * XS + g * 8;
                    dg[r][b] += a0 * xp[0] + a1 * xp[1] + a2 * xp[2] + a3 * xp[3]
                              + a4 * xp[4] + a5 * xp[5] + a6 * xp[6] + a7 * xp[7];
                }
            }
        }
        const uint4* __restrict__ w2 =
            reinterpret_cast<const uint4*>(whh + (size_t)(j + r * 512) * 512);
#pragma unroll
        for (int gi = 0; gi < 8; ++gi) {
            int g = gi * 8 + sub;
            uint4 u = w2[g];
            float a0 = bflo(u.x), a1 = bfhi(u.x), a2 = bflo(u.y), a3 = bfhi(u.y);
            float a4 = bflo(u.z), a5 = bfhi(u.z), a6 = bflo(u.w), a7 = bfhi(u.w);
#pragma unroll
            for (int b = 0; b < 4; ++b) {
                const float* xp = xs0 + b * XS + K1 + g * 8;
                dg[r][b] += a0 * xp[0] + a1 * xp[1] + a2 * xp[2] + a3 * xp[3]
                          + a4 * xp[4] + a5 * xp[5] + a6 * xp[6] + a7 * xp[7];
            }
        }
    }
}

// per-layer persistent loop. NB1=9 (layer 0, K1=72) or 72 (layers 1-5, K1=576).
template <int NB1>
__device__ inline void lstm_layer_loop(
    int l, int bx,
    const bf16* __restrict__ wih, const bf16* __restrict__ whh,
    const float* __restrict__ bih, const float* __restrict__ bhh,
    const float* __restrict__ states,
    const float* __restrict__ featm, const float* __restrict__ feats,
    float* __restrict__ hAll, float* __restrict__ cst,
    int* __restrict__ fl, float* __restrict__ xs)
{
    constexpr int K1 = NB1 * 8;
    constexpr int XS = K1 + 512;
    const int tid = threadIdx.x;
    const int jloc = tid >> 3;           // 0..31
    const int sub = tid & 7;             // 0..7
    const int j = bx * 32 + jloc;

    for (int t = 0; t < 10; ++t) {
        // polls are RMWs at the LLC (fresh); one lane per producer flag.
        // lanes 0..15 -> producer layer (l-1) >= t+1; 64..79 -> own layer >= t
        if (l > 0 && tid < 16) {
            while (flag_poll(&fl[((l - 1) * 16 + tid) * 16]) < t + 1)
                __builtin_amdgcn_s_sleep(32);
        }
        if (t > 0 && tid >= 64 && tid < 80) {
            while (flag_poll(&fl[(l * 16 + (tid - 64)) * 16]) < t)
                __builtin_amdgcn_s_sleep(32);
        }
        __syncthreads();

        const float* hprev = (l == 0) ? nullptr
                           : hAll + ((size_t)(t + 1) * 6 + (l - 1)) * 2048;
        const float* hold  = hAll + ((size_t)t * 6 + l) * 2048;
        float* hnew        = hAll + ((size_t)(t + 1) * 6 + l) * 2048;

        if (NB1 == 72) {
            // per b: [0,512)=hprev, [512,576)=feat, [576,1088)=hold
            for (int i = tid; i < 4 * 512; i += 256) {
                int bb = i >> 9, kk = i & 511;      // 64-bit pair index
                union { unsigned long long u; float f[2]; } cv;
                int base;
                if (kk < 256) { cv.u = devload2(&hprev[bb * 512 + kk * 2]); base = bb * XS + kk * 2; }
                else { cv.u = devload2(&hold[bb * 512 + (kk - 256) * 2]); base = bb * XS + 576 + (kk - 256) * 2; }
                xs[base] = cv.f[0]; xs[base + 1] = cv.f[1];
            }
            {
                int bb = tid >> 6, k = tid & 63;
                xs[bb * XS + 512 + k] = imgfeat(featm, feats, bb, t, k);
            }
        } else {
            // per b: [0,6)=states, [6,70)=feat, [70,72)=0, [72,584)=hold
            for (int i = tid; i < 4 * 256; i += 256) {
                int bb = i >> 8, kk = i & 255;
                union { unsigned long long u; float f[2]; } cv;
                cv.u = devload2(&hold[bb * 512 + kk * 2]);
                int base = bb * XS + 72 + kk * 2;
                xs[base] = cv.f[0]; xs[base + 1] = cv.f[1];
            }
            for (int i = tid; i < 4 * 72; i += 256) {
                int bb = i / 72, k = i - bb * 72;
                float v = (k < 6) ? states[(bb * 10 + t) * 6 + k]
                                  : (k < 70 ? imgfeat(featm, feats, bb, t, k - 6) : 0.f);
                xs[bb * XS + k] = v;
            }
        }
        __syncthreads();

        float dg[4][4] = {{0.f, 0.f, 0.f, 0.f}, {0.f, 0.f, 0.f, 0.f},
                          {0.f, 0.f, 0.f, 0.f}, {0.f, 0.f, 0.f, 0.f}};
        cell_mm<NB1>(wih, whh, xs, j, sub, dg);

#pragma unroll
        for (int r = 0; r < 4; ++r)
#pragma unroll
            for (int b = 0; b < 4; ++b) {
                dg[r][b] += __shfl_xor(dg[r][b], 1);
                dg[r][b] += __shfl_xor(dg[r][b], 2);
                dg[r][b] += __shfl_xor(dg[r][b], 4);
            }

        if (sub == 0) {
            float b0 = bih[j] + bhh[j];
            float b1 = bih[j + 512] + bhh[j + 512];
            float b2 = bih[j + 1024] + bhh[j + 1024];
            float b3 = bih[j + 1536] + bhh[j + 1536];
#pragma unroll
            for (int b = 0; b < 4; ++b) {
                float gi = dg[0][b] + b0;
                float gf = dg[1][b] + b1;
                float gg = dg[2][b] + b2;
                float go = dg[3][b] + b3;
                float cp = cst[b * 512 + j];
                float c2 = sigmoidf_(gf) * cp + sigmoidf_(gi) * tanhf(gg);
                float h2 = sigmoidf_(go) * tanhf(c2);
                cst[b * 512 + j] = c2;
                devstore(&hnew[b * 512 + j], h2);
            }
        }
        // __syncthreads drains vmcnt (h stores acked at LLC) before flag post
        __syncthreads();
        if (tid == 0) flag_post(&fl[(l * 16 + bx) * 16]);
    }
}

// ---------------- LSTM: persistent pipeline, RMW-poll p2p flags -------------
// grid = 6*16 + 1 = 97 blocks -> every block on its own CU.
// Layer l owns blocks [l*16, (l+1)*16); block bx owns gates j in [bx*32,+32).
// Each flag on its own 64B line; polls via fetch_max RMW (coherence-point
// fresh), posts via fetch_add. Data via relaxed agent loads (read-once
// addresses -> always miss -> always fresh; verified R3-R6).
__global__ __launch_bounds__(256) void lstm_pipe2_k(
    const bf16* __restrict__ wih0p, const bf16* __restrict__ whh0b,
    const bf16* __restrict__ wihrb, const bf16* __restrict__ whhrb,
    const float* __restrict__ bih0, const float* __restrict__ bhh0,
    const float* __restrict__ bihr, const float* __restrict__ bhhr,
    const float* __restrict__ states,
    const float* __restrict__ featm, const float* __restrict__ feats,
    float* __restrict__ hAll, float* __restrict__ cAll,
    const float* __restrict__ out_w, const float* __restrict__ out_b,
    float* __restrict__ out, int* __restrict__ fl)
{
    const int gb = blockIdx.x;
    const int tid = threadIdx.x;
    __shared__ float xs[4 * 1088];

    if (gb == 6 * NBL) {            // out-projection block: consumes h5[t]
        for (int t = 0; t < 10; ++t) {
            if (tid < 16) {
                while (flag_poll(&fl[(5 * 16 + tid) * 16]) < t + 1)
                    __builtin_amdgcn_s_sleep(32);
            }
            __syncthreads();
            const float* h5 = hAll + ((size_t)(t + 1) * 6 + 5) * 2048;
            int p = tid >> 3, sub = tid & 7;
            if (p < 24) {
                int b = p / 6, a = p % 6;
                const float* wr = out_w + a * 576;
                float acc = 0.f;
                for (int k = sub; k < 256; k += 8) {
                    union { unsigned long long u; float f[2]; } cv;
                    cv.u = devload2(&h5[b * 512 + k * 2]);
                    acc += wr[k * 2] * cv.f[0] + wr[k * 2 + 1] * cv.f[1];
                }
                for (int k = sub; k < 64; k += 8)
                    acc += wr[512 + k] * imgfeat(featm, feats, b, t, k);
                acc += __shfl_xor(acc, 1);
                acc += __shfl_xor(acc, 2);
                acc += __shfl_xor(acc, 4);
                if (sub == 0) out[(b * 10 + t) * 6 + a] = acc + out_b[a];
            }
            __syncthreads();
        }
        return;
    }

    const int l = gb / NBL;
    const int bx = gb % NBL;

    const bf16 *wih, *whh;
    const float *bih, *bhh;
    if (l == 0) { wih = wih0p; whh = whh0b; bih = bih0; bhh = bhh0; }
    else {
        wih = wihrb + (size_t)(l - 1) * 2048 * 576;
        whh = whhrb + (size_t)(l - 1) * 2048 * 512;
        bih = bihr + (l - 1) * 2048;
        bhh = bhhr + (l - 1) * 2048;
    }
    float* cst = cAll + (size_t)l * 2048;

    if (l == 0)
        lstm_layer_loop<9>(l, bx, wih, whh, bih, bhh, states, featm, feats,
                           hAll, cst, fl, xs);
    else
        lstm_layer_loop<72>(l, bx, wih, whh, bih, bhh, states, featm, feats,
                            hAll, cst, fl, xs);
}

// ---------------- host orchestration ----------------------------------------
extern "C" void kernel_launch(void* const* d_in, const int* in_sizes, int n_in,
                              void* d_out, int out_size, void* d_ws, size_t ws_size,
                              hipStream_t stream)
{
    const float* seq_m = (const float*)d_in[0];
    const float* seq_s = (const float*)d_in[1];
    const float* states = (const float*)d_in[2];
    const float *cw[2][4], *cb[2][4];
    for (int cam = 0; cam < 2; ++cam)
        for (int j = 0; j < 4; ++j) {
            cw[cam][j] = (const float*)d_in[3 + cam * 8 + j * 2];
            cb[cam][j] = (const float*)d_in[3 + cam * 8 + j * 2 + 1];
        }
    const float* wih0  = (const float*)d_in[19];
    const float* whh0  = (const float*)d_in[20];
    const float* bih0  = (const float*)d_in[21];
    const float* bhh0  = (const float*)d_in[22];
    const float* wih_r = (const float*)d_in[23];
    const float* whh_r = (const float*)d_in[24];
    const float* bih_r = (const float*)d_in[25];
    const float* bhh_r = (const float*)d_in[26];
    const float* out_w = (const float*)d_in[27];
    const float* out_b = (const float*)d_in[28];
    float* out = (float*)d_out;

    // ---- workspace carve (256B-aligned) ----
    char* wsc = (char*)d_ws;
    auto carve = [&](size_t bytes) {
        char* p = wsc;
        wsc += (bytes + 255) & ~(size_t)255;
        return p;
    };
    float* featm = (float*)carve(40 * 32 * 4);
    float* feats = (float*)carve(40 * 32 * 4);
    float* hAll  = (float*)carve((size_t)11 * 6 * 2048 * 4);
    float* cAll  = (float*)carve((size_t)6 * 2048 * 4);
    char*  zpage = carve(8192);
    int*   lcnt  = (int*)carve((size_t)6 * NBL * 16 * 4);   // 64B-padded flags
    float* partial = (float*)carve((size_t)80 * 16 * 256 * 4 * 4);
    const int wtElts[4] = {3072, 18432, 73728, 18432};
    bf16* wT[2][4];
    for (int cam = 0; cam < 2; ++cam)
        for (int j = 0; j < 4; ++j) wT[cam][j] = (bf16*)carve(wtElts[j] * 2);
    bf16* wih0p = (bf16*)carve((size_t)2048 * 72 * 2);
    bf16* whh0b = (bf16*)carve((size_t)2048 * 512 * 2);
    bf16* wihrb = (bf16*)carve((size_t)5 * 2048 * 576 * 2);
    bf16* whhrb = (bf16*)carve((size_t)5 * 2048 * 512 * 2);

    size_t used = (size_t)(wsc - (char*)d_ws);
    size_t rem = ws_size > used ? ws_size - used : 0;
    int CHI = 1;
    const int cands[7] = {20, 10, 8, 5, 4, 2, 1};
    for (int i = 0; i < 7; ++i) {
        size_t need = (size_t)2 * cands[i] * (128 + 64) * HWPX * 2;
        if (need <= rem) { CHI = cands[i]; break; }
    }
    bf16* bufA = (bf16*)carve((size_t)2 * CHI * HWPX * 128 * 2);
    bf16* bufB = (bf16*)carve((size_t)2 * CHI * HWPX * 64 * 2);

    hipMemsetAsync(hAll, 0, 6 * 2048 * 4, stream);       // t=-1 slot
    hipMemsetAsync(cAll, 0, 6 * 2048 * 4, stream);
    hipMemsetAsync(zpage, 0, 8192, stream);
    hipMemsetAsync(lcnt, 0, 6 * NBL * 16 * 4, stream);   // p2p flags

    // ---- weight preps ----
    prep_lstm_k<<<2048, 256, 0, stream>>>(wih0, whh0, wih_r, whh_r,
                                          wih0p, whh0b, wihrb, whhrb);
    ConvW cwArg;
    for (int cam = 0; cam < 2; ++cam)
        for (int j = 0; j < 4; ++j) {
            cwArg.src[cam * 4 + j] = cw[cam][j];
            cwArg.dst[cam * 4 + j] = wT[cam][j];
        }
    prep_conv_k<<<888, 256, 0, stream>>>(cwArg);

    // ---- CNN + fused spatial softmax (both cams per dispatch) ----
    for (int c0 = 0; c0 < 40; c0 += CHI) {
        int ch = (40 - c0) < CHI ? (40 - c0) : CHI;
        conv0_nhwc<<<dim3(128, 2, ch), 256, 0, stream>>>(
            seq_m, seq_s, wT[0][0], wT[1][0], cb[0][0], cb[1][0], bufA, c0);
        conv2r<32, 64><<<dim3(128, 2, ch), 256, 0, stream>>>(
            bufA, wT[0][1], wT[1][1], cb[0][1], cb[1][1], bufB, zpage);
        conv2r<64, 128><<<dim3(128, 2, ch), 256, 0, stream>>>(
            bufB, wT[0][2], wT[1][2], cb[0][2], cb[1][2], bufA, zpage);
        conv4_xs<<<dim3(256, 2, ch), 256, 0, stream>>>(
            bufA, wT[0][3], wT[1][3], cb[0][3], cb[1][3], partial, zpage, c0);
    }
    ssmerge_k<<<80, 256, 0, stream>>>(partial, featm, feats);

    // ---- LSTM: one persistent kernel, RMW-poll flag pipeline ---------------
    lstm_pipe2_k<<<dim3(6 * NBL + 1), 256, 0, stream>>>(
        wih0p, whh0b, wihrb, whhrb, bih0, bhh0, bih_r, bhh_r,
        states, featm, feats, hAll, cAll, out_w, out_b, out, lcnt);
}

// Round 8
// 1131.555 us; speedup vs baseline: 1.0784x; 1.0784x over previous
//
#include <hip/hip_runtime.h>
#include <hip/hip_bf16.h>
#include <math.h>

typedef __hip_bfloat16 bf16;
typedef short bf16x8 __attribute__((ext_vector_type(8)));
typedef float f32x4 __attribute__((ext_vector_type(4)));

static constexpr int HWPX = 16384;   // 128*128

__device__ inline float sigmoidf_(float x) { return 1.0f / (1.0f + expf(-x)); }
__device__ inline float bflo(unsigned u) { return __uint_as_float(u << 16); }
__device__ inline float bfhi(unsigned u) { return __uint_as_float(u & 0xffff0000u); }
__device__ inline int swz(int x) { return (x ^ (x >> 2)) & 3; }

// async global->LDS, 16B per lane; lds base wave-uniform (lane i -> +i*16)
__device__ inline void gll16(const bf16* g, short* l) {
    __builtin_amdgcn_global_load_lds(
        (const __attribute__((address_space(1))) void*)g,
        (__attribute__((address_space(3))) void*)l, 16, 0, 0);
}

// ---------------- prep: LSTM weights -> bf16 (wih0 padded 70->72) -----------
__global__ __launch_bounds__(256) void prep_lstm_k(
    const float* __restrict__ wih0, const float* __restrict__ whh0,
    const float* __restrict__ wihr, const float* __restrict__ whhr,
    bf16* __restrict__ d0, bf16* __restrict__ d1,
    bf16* __restrict__ d2, bf16* __restrict__ d3)
{
    const size_t nA = 2048ull * 72, nB = 2048ull * 512;
    const size_t nC = 5ull * 2048 * 576, nD = 5ull * 2048 * 512;
    for (size_t i = blockIdx.x * 256ull + threadIdx.x; i < nA + nB + nC + nD;
         i += (size_t)gridDim.x * 256) {
        if (i < nA) {
            int c = (int)(i % 72), r = (int)(i / 72);
            d0[i] = __float2bfloat16(c < 70 ? wih0[(size_t)r * 70 + c] : 0.f);
        } else if (i < nA + nB) {
            size_t k = i - nA; d1[k] = __float2bfloat16(whh0[k]);
        } else if (i < nA + nB + nC) {
            size_t k = i - nA - nB; d2[k] = __float2bfloat16(wihr[k]);
        } else {
            size_t k = i - nA - nB - nC; d3[k] = __float2bfloat16(whhr[k]);
        }
    }
}

// ---------------- prep: conv weights, both cams -----------------------------
struct ConvW {
    const float* src[8];
    bf16* dst[8];
};

__global__ __launch_bounds__(256) void prep_conv_k(ConvW a)
{
    const int sizes[4] = {3072, 18432, 73728, 18432};
    const int cins[4] = {3, 32, 64, 128};
    const int couts[4] = {32, 64, 128, 16};
    int total = 2 * 113664;
    for (int idx = blockIdx.x * 256 + threadIdx.x; idx < total; idx += gridDim.x * 256) {
        int i = idx, cam = 0;
        if (i >= 113664) { cam = 1; i -= 113664; }
        int layer = 0;
        while (layer < 3 && i >= sizes[layer]) { i -= sizes[layer]; ++layer; }
        const float* w = a.src[cam * 4 + layer];
        bf16* d = a.dst[cam * 4 + layer];
        if (layer == 0) {
            // [3ky][32co][32k], k = kx*8 + c
            int k = i & 31, co = (i >> 5) & 31, ky = i >> 10;
            int kx = k >> 3, c = k & 7;
            float v = (kx < 3 && c < 3) ? w[((co * 3 + c) * 3 + ky) * 3 + kx] : 0.f;
            d[i] = __float2bfloat16(v);
        } else {
            // dst [tap][kc][q][co][8]
            int CIN = cins[layer], COUT = couts[layer], KC = CIN / 32;
            int e = i & 7;
            int t2 = i >> 3;
            int co = t2 % COUT;
            int t3 = t2 / COUT;
            int q = t3 & 3;
            int t4 = t3 >> 2;
            int kc = t4 % KC;
            int tap = t4 / KC;
            d[i] = __float2bfloat16(w[((size_t)(co * CIN + kc * 32 + q * 8 + e)) * 9 + tap]);
        }
    }
}

// ---------------- fused conv0+conv1: raw fp32 -> 64ch bf16 ------------------
// Block = 2 output rows x 64 px (same tiling as conv2r<32,64>).
// Phase A: stage raw 6x68x3 fp32 halo -> LDS fragments; conv0 via MFMA
//   (identical op order to the old conv0_nhwc -> bit-identical values)
//   written directly into the granule-swizzled slot layout conv1 reads.
// Phase B: conv1 (32->64) exactly as conv2r<32,64> computed it.
// Kills the conv0 dispatches and the bufA-32 HBM round trip.
__global__ __launch_bounds__(256, 4) void conv01(
    const float* __restrict__ srcm, const float* __restrict__ srcs,
    const bf16* __restrict__ w0m, const bf16* __restrict__ w0s,
    const float* __restrict__ b0m, const float* __restrict__ b0s,
    const bf16* __restrict__ wTm, const bf16* __restrict__ wTs,
    const float* __restrict__ bm, const float* __restrict__ bs,
    bf16* __restrict__ out, int c0)
{
    constexpr int COUT = 64, MW = 2;          // conv1: 32 -> 64
    constexpr int SLOTS = 4 * 264;            // 4 rows x 66 px x 4 granules

    const int y0 = (blockIdx.x >> 1) * 2;
    const int x0 = (blockIdx.x & 1) * 64;
    const int cam = blockIdx.y;
    const int img = blockIdx.z;
    const int ci_ = cam * gridDim.z + img;
    const float* inImg = (cam ? srcs : srcm) + (size_t)(c0 + img) * 3 * HWPX;
    const bf16* wT0 = cam ? w0s : w0m;
    const float* bias0 = cam ? b0s : b0m;
    const bf16* wT = cam ? wTs : wTm;
    const float* bias = cam ? bs : bm;
    const int tid = threadIdx.x;
    const int wave = tid >> 6, lane = tid & 63;
    const int wrow = wave >> 1, wm = wave & 1;
    const int q = lane >> 4, n16 = lane & 15;

    __shared__ short smem[SLOTS * 8];         // conv0 out / conv1 in
    __shared__ short raw[6 * 68 * 16];        // conv0 input fragments

    // zero conv0-out region (border rows/px stay zero = SAME padding)
    for (int i = tid; i < SLOTS; i += 256)
        *(bf16x8*)(void*)&smem[i * 8] = (bf16x8)0;

    // stage raw halo: rows y0-2..y0+3, px x0-2..x0+65, 3 channels
    for (int d = tid; d < 6 * 68; d += 256) {
        int x = d % 68, r = d / 68;
        int yy = y0 - 2 + r, xx = x0 - 2 + x;
        bf16 v8[8];
#pragma unroll
        for (int c = 0; c < 8; ++c) v8[c] = __float2bfloat16(0.f);
        if ((unsigned)yy < 128u && (unsigned)xx < 128u) {
            int o = yy * 128 + xx;
            v8[0] = __float2bfloat16(inImg[o]);
            v8[1] = __float2bfloat16(inImg[HWPX + o]);
            v8[2] = __float2bfloat16(inImg[2 * HWPX + o]);
        }
        *(bf16x8*)(void*)&raw[d * 16] = *(bf16x8*)(void*)v8;
        *(bf16x8*)(void*)&raw[d * 16 + 8] = (bf16x8)0;
    }
    __syncthreads();

    // conv0 MFMA: rows rp=0..3 (global y0-1+rp), px xt (global x0-1+xt)
    const int co0_ = wm * 16 + n16;
    for (int rp = 0; rp < 4; ++rp) {
        int Y = y0 - 1 + rp;
        if ((unsigned)Y >= 128u) continue;     // wave-uniform; stays zero
        for (int xg = wrow; xg < 5; xg += 2) { // waves split px-groups
            int xt = xg * 16 + n16;
            int xts = xt < 66 ? xt : 65;       // clamp to keep LDS reads legal
            f32x4 a0 = f32x4{0.f, 0.f, 0.f, 0.f};
#pragma unroll
            for (int ky = 0; ky < 3; ++ky) {
                bf16x8 aF = *(const bf16x8*)(const void*)(wT0 +
                    ((size_t)(ky * 32 + co0_) * 32) + q * 8);
                int off = (q < 3) ? ((rp + ky) * 68 + xts + q) * 16
                                  : ((rp + ky) * 68 + xts) * 16 + 8;
                bf16x8 bF = *(const bf16x8*)(const void*)&raw[off];
                a0 = __builtin_amdgcn_mfma_f32_16x16x32_bf16(aF, bF, a0, 0, 0, 0);
            }
            int X = x0 - 1 + xt;
            if (xt < 66 && (unsigned)X < 128u) {
                int cb0 = wm * 16 + q * 4;
                bf16 tmp[4];
#pragma unroll
                for (int r = 0; r < 4; ++r) {
                    float v = a0[r] + bias0[cb0 + r];
                    tmp[r] = __float2bfloat16(v > 0.f ? v : 0.f);
                }
                int g = cb0 >> 3;                       // granule 0..3
                int sbase = (rp * 264 + xt * 4 + (g ^ swz(xt))) * 8 + (q & 1) * 4;
                *reinterpret_cast<uint2*>(&smem[sbase]) = *reinterpret_cast<uint2*>(tmp);
            }
        }
    }
    __syncthreads();

    // conv1 compute (identical to conv2r<32,64> inner loop, KC=1)
    f32x4 acc[MW][4];
#pragma unroll
    for (int mt = 0; mt < MW; ++mt)
#pragma unroll
        for (int nt = 0; nt < 4; ++nt) acc[mt][nt] = f32x4{0.f, 0.f, 0.f, 0.f};

#pragma unroll
    for (int ky = 0; ky < 3; ++ky) {
#pragma unroll
        for (int kx = 0; kx < 3; ++kx) {
            bf16x8 aF[MW];
#pragma unroll
            for (int mt = 0; mt < MW; ++mt) {
                int co = (wm * MW + mt) * 16 + n16;
                aF[mt] = *(const bf16x8*)(const void*)(wT +
                    (((size_t)(ky * 3 + kx) * 4 + q) * COUT + co) * 8);
            }
#pragma unroll
            for (int nt = 0; nt < 4; ++nt) {
                int xt = nt * 16 + n16 + kx;           // 0..65
                int slot = (wrow + ky) * 264 + xt * 4 + (q ^ swz(xt));
                bf16x8 bF = *(const bf16x8*)(const void*)&smem[slot * 8];
#pragma unroll
                for (int mt = 0; mt < MW; ++mt)
                    acc[mt][nt] = __builtin_amdgcn_mfma_f32_16x16x32_bf16(
                        aF[mt], bF, acc[mt][nt], 0, 0, 0);
            }
        }
    }

    const int y = y0 + wrow;
#pragma unroll
    for (int mt = 0; mt < MW; ++mt) {
        int co0 = (wm * MW + mt) * 16 + q * 4;
#pragma unroll
        for (int nt = 0; nt < 4; ++nt) {
            int x = x0 + nt * 16 + n16;
            bf16 tmp[4];
#pragma unroll
            for (int r = 0; r < 4; ++r) {
                float v = acc[mt][nt][r] + bias[co0 + r];
                tmp[r] = __float2bfloat16(v > 0.f ? v : 0.f);
            }
            *reinterpret_cast<uint2*>(out + ((size_t)ci_ * HWPX + y * 128 + x) * COUT + co0)
                = *reinterpret_cast<uint2*>(tmp);
        }
    }
}

// ---------------- mid convs: 2 rows x 64px per block, gll dbuf --------------
template <int CIN, int COUT>
__global__ __launch_bounds__(256, 4) void conv2r(
    const bf16* __restrict__ in, const bf16* __restrict__ wTm,
    const bf16* __restrict__ wTs, const float* __restrict__ bm,
    const float* __restrict__ bs, bf16* __restrict__ out,
    const char* __restrict__ zpage)
{
    constexpr int KC = CIN / 32;
    constexpr int NB = (KC > 1) ? 2 : 1;
    constexpr int MW = COUT / 32;       // co tiles per wave (2 co-halves)
    constexpr int SLOTS = 4 * 264;      // 4 rows x 66 x x 4 granules

    const int y0 = (blockIdx.x >> 1) * 2;
    const int x0 = (blockIdx.x & 1) * 64;
    const int cam = blockIdx.y;
    const int img = blockIdx.z;
    const int ci_ = cam * gridDim.z + img;
    const bf16* wT = cam ? wTs : wTm;
    const float* bias = cam ? bs : bm;
    const int tid = threadIdx.x;
    const int wave = tid >> 6, lane = tid & 63;
    const int wrow = wave >> 1, wm = wave & 1;
    const int q = lane >> 4, n16 = lane & 15;

    __shared__ short smem[NB][SLOTS * 8];
    const bf16* inImg = in + (size_t)ci_ * HWPX * CIN;

    const bf16* sptr[5];
#pragma unroll
    for (int it = 0; it < 5; ++it) {
        int s = it * 256 + tid;
        int r = s / 264, s2 = s - r * 264;
        int sx = s2 >> 2;
        int g = (s2 & 3) ^ swz(sx);
        int yy = y0 + r - 1, xx = x0 + sx - 1;
        bool ok = (s < SLOTS) && ((unsigned)yy < 128u) && ((unsigned)xx < 128u);
        sptr[it] = ok ? inImg + ((size_t)yy * 128 + xx) * CIN + g * 8
                      : (const bf16*)(zpage + (tid & 255) * 16);
    }
    auto stage = [&](int kc, int buf) {
#pragma unroll
        for (int it = 0; it < 5; ++it) {
            if (it * 256 + tid < SLOTS)
                gll16(sptr[it] + kc * 32, &smem[buf][it * 2048 + wave * 512]);
        }
    };

    f32x4 acc[MW][4];
#pragma unroll
    for (int mt = 0; mt < MW; ++mt)
#pragma unroll
        for (int nt = 0; nt < 4; ++nt) acc[mt][nt] = f32x4{0.f, 0.f, 0.f, 0.f};

    stage(0, 0);
    for (int kc = 0; kc < KC; ++kc) {
        __syncthreads();
        if (kc + 1 < KC) stage(kc + 1, (kc + 1) % NB);
        const short* sb = smem[kc % NB];
#pragma unroll
        for (int ky = 0; ky < 3; ++ky) {
#pragma unroll
            for (int kx = 0; kx < 3; ++kx) {
                bf16x8 aF[MW];
#pragma unroll
                for (int mt = 0; mt < MW; ++mt) {
                    int co = (wm * MW + mt) * 16 + n16;
                    aF[mt] = *(const bf16x8*)(const void*)(wT +
                        ((((size_t)(ky * 3 + kx) * KC + kc) * 4 + q) * COUT + co) * 8);
                }
#pragma unroll
                for (int nt = 0; nt < 4; ++nt) {
                    int xt = nt * 16 + n16 + kx;           // 0..65
                    int slot = (wrow + ky) * 264 + xt * 4 + (q ^ swz(xt));
                    bf16x8 bF = *(const bf16x8*)(const void*)&sb[slot * 8];
#pragma unroll
                    for (int mt = 0; mt < MW; ++mt)
                        acc[mt][nt] = __builtin_amdgcn_mfma_f32_16x16x32_bf16(
                            aF[mt], bF, acc[mt][nt], 0, 0, 0);
                }
            }
        }
    }

    const int y = y0 + wrow;
#pragma unroll
    for (int mt = 0; mt < MW; ++mt) {
        int co0 = (wm * MW + mt) * 16 + q * 4;
#pragma unroll
        for (int nt = 0; nt < 4; ++nt) {
            int x = x0 + nt * 16 + n16;
            bf16 tmp[4];
#pragma unroll
            for (int r = 0; r < 4; ++r) {
                float v = acc[mt][nt][r] + bias[co0 + r];
                tmp[r] = __float2bfloat16(v > 0.f ? v : 0.f);
            }
            *reinterpret_cast<uint2*>(out + ((size_t)ci_ * HWPX + y * 128 + x) * COUT + co0)
                = *reinterpret_cast<uint2*>(tmp);
        }
    }
}

// ---------------- conv4 (128->16): half-row x-split + softmax partials ------
__global__ __launch_bounds__(256, 6) void conv4_xs(
    const bf16* __restrict__ in, const bf16* __restrict__ wTm,
    const bf16* __restrict__ wTs, const float* __restrict__ bm,
    const float* __restrict__ bs,
    float* __restrict__ partial,   // [gimg][16][256] x {M,S,SX,-}
    const char* __restrict__ zpage, int c0)
{
    constexpr int CIN = 128, COUT = 16, KC = 4;
    constexpr int SLOTS = 3 * 66 * 4;
    const int y = blockIdx.x >> 1;
    const int xh = blockIdx.x & 1;
    const int x0 = xh * 64;
    const int cam = blockIdx.y;
    const int img = blockIdx.z;
    const int ci_ = cam * gridDim.z + img;
    const int gimg = cam * 40 + c0 + img;
    const bf16* wT = cam ? wTs : wTm;
    const float* bias = cam ? bs : bm;
    const int tid = threadIdx.x;
    const int wave = tid >> 6, lane = tid & 63;
    const int q = lane >> 4, n16 = lane & 15;

    __shared__ short smem[2][SLOTS * 8];
    __shared__ float sred[3][4][16];
    const bf16* inImg = in + (size_t)ci_ * HWPX * CIN;

    const bf16* sptr[4];
#pragma unroll
    for (int it = 0; it < 4; ++it) {
        int s = it * 256 + tid;
        int r = s / 264, s2 = s - r * 264;
        int sx = s2 >> 2;
        int g = (s2 & 3) ^ swz(sx);
        int yy = y + r - 1, xx = x0 + sx - 1;
        bool ok = (s < SLOTS) && ((unsigned)yy < 128u) && ((unsigned)xx < 128u);
        sptr[it] = ok ? inImg + ((size_t)yy * 128 + xx) * CIN + g * 8
                      : (const bf16*)(zpage + (tid & 255) * 16);
    }
    auto stage = [&](int kc, int buf) {
#pragma unroll
        for (int it = 0; it < 4; ++it) {
            if (it * 256 + tid < SLOTS)
                gll16(sptr[it] + kc * 32, &smem[buf][it * 2048 + wave * 512]);
        }
    };

    f32x4 acc = f32x4{0.f, 0.f, 0.f, 0.f};

    stage(0, 0);
    for (int kc = 0; kc < KC; ++kc) {
        __syncthreads();
        if (kc + 1 < KC) stage(kc + 1, (kc + 1) & 1);
        const short* sb = smem[kc & 1];
#pragma unroll
        for (int ky = 0; ky < 3; ++ky) {
#pragma unroll
            for (int kx = 0; kx < 3; ++kx) {
                bf16x8 aF = *(const bf16x8*)(const void*)(wT +
                    ((((size_t)(ky * 3 + kx) * KC + kc) * 4 + q) * COUT + n16) * 8);
                int xt = wave * 16 + n16 + kx;
                int slot = xt * 4 + (q ^ swz(xt));
                bf16x8 bF = *(const bf16x8*)(const void*)&sb[ky * 2112 + slot * 8];
                acc = __builtin_amdgcn_mfma_f32_16x16x32_bf16(aF, bF, acc, 0, 0, 0);
            }
        }
    }

    // bias + relu; online partials over this 64px half-row (co = q*4+r)
    float v[4];
    int x = x0 + wave * 16 + n16;
    float px = -1.f + (2.f / 127.f) * x;
#pragma unroll
    for (int r = 0; r < 4; ++r) {
        float t = acc[r] + bias[q * 4 + r];
        v[r] = t > 0.f ? t : 0.f;
    }
    float M[4];
#pragma unroll
    for (int r = 0; r < 4; ++r) {
        M[r] = v[r];
        M[r] = fmaxf(M[r], __shfl_xor(M[r], 1));
        M[r] = fmaxf(M[r], __shfl_xor(M[r], 2));
        M[r] = fmaxf(M[r], __shfl_xor(M[r], 4));
        M[r] = fmaxf(M[r], __shfl_xor(M[r], 8));
    }
    if (n16 == 0)
#pragma unroll
        for (int r = 0; r < 4; ++r) sred[0][wave][q * 4 + r] = M[r];
    __syncthreads();
#pragma unroll
    for (int r = 0; r < 4; ++r) {
        M[r] = fmaxf(fmaxf(sred[0][0][q * 4 + r], sred[0][1][q * 4 + r]),
                     fmaxf(sred[0][2][q * 4 + r], sred[0][3][q * 4 + r]));
    }
    float s[4], sx[4];
#pragma unroll
    for (int r = 0; r < 4; ++r) {
        float e = expf(v[r] - M[r]);
        s[r] = e; sx[r] = e * px;
        s[r] += __shfl_xor(s[r], 1);  sx[r] += __shfl_xor(sx[r], 1);
        s[r] += __shfl_xor(s[r], 2);  sx[r] += __shfl_xor(sx[r], 2);
        s[r] += __shfl_xor(s[r], 4);  sx[r] += __shfl_xor(sx[r], 4);
        s[r] += __shfl_xor(s[r], 8);  sx[r] += __shfl_xor(sx[r], 8);
    }
    __syncthreads();
    if (n16 == 0)
#pragma unroll
        for (int r = 0; r < 4; ++r) {
            sred[1][wave][q * 4 + r] = s[r];
            sred[2][wave][q * 4 + r] = sx[r];
        }
    __syncthreads();
    if (tid < 16) {
        float S = sred[1][0][tid] + sred[1][1][tid] + sred[1][2][tid] + sred[1][3][tid];
        float SX = sred[2][0][tid] + sred[2][1][tid] + sred[2][2][tid] + sred[2][3][tid];
        float Mv = fmaxf(fmaxf(sred[0][0][tid], sred[0][1][tid]),
                         fmaxf(sred[0][2][tid], sred[0][3][tid]));
        float* pp = partial + (((size_t)gimg * 16 + tid) * 256 + (y * 2 + xh)) * 4;
        pp[0] = Mv; pp[1] = S; pp[2] = SX;
    }
}

// ---------------- merge partials -> (ex, ey), both cams ---------------------
__global__ __launch_bounds__(256) void ssmerge_k(
    const float* __restrict__ partial, float* __restrict__ featm,
    float* __restrict__ feats)
{
    const int img = blockIdx.x;          // 0..79
    const int cam = img / 40, li = img % 40;
    float* feat = cam ? feats : featm;
    const int tid = threadIdx.x;
    const int co = tid >> 4, s = tid & 15;
    const float* base = partial + ((size_t)img * 16 + co) * 256 * 4;
    float M = -1e30f, S = 0.f, SX = 0.f, SY = 0.f;
    for (int i = s; i < 256; i += 16) {
        float m = base[i * 4], sv = base[i * 4 + 1], sxv = base[i * 4 + 2];
        float py = -1.f + (2.f / 127.f) * (i >> 1);
        float Mn = fmaxf(M, m);
        float w0 = expf(M - Mn), w1 = expf(m - Mn);
        S = S * w0 + sv * w1;
        SX = SX * w0 + sxv * w1;
        SY = SY * w0 + sv * py * w1;
        M = Mn;
    }
#pragma unroll
    for (int mask = 1; mask < 16; mask <<= 1) {
        float Mo = __shfl_xor(M, mask), So = __shfl_xor(S, mask);
        float SXo = __shfl_xor(SX, mask), SYo = __shfl_xor(SY, mask);
        float Mn = fmaxf(M, Mo);
        float w0 = expf(M - Mn), w1 = expf(Mo - Mn);
        S = S * w0 + So * w1; SX = SX * w0 + SXo * w1; SY = SY * w0 + SYo * w1;
        M = Mn;
    }
    if (s == 0) {
        feat[(size_t)li * 32 + 2 * co] = SX / S;
        feat[(size_t)li * 32 + 2 * co + 1] = SY / S;
    }
}

// ---------------- LSTM helpers ----------------------------------------------
__device__ inline float imgfeat(const float* featm, const float* feats,
                                int b, int t, int k)
{
    int idx = (b * 10 + t) * 32;
    return k < 32 ? featm[idx + k] : feats[idx + k - 32];
}

// per-thread GEMV slice: 32-gate block, all 4 batches folded into the thread.
// NB1 = K1/8 (compile-time) -> fully unrolled, pipelined weight loads.
// (verified correct in rounds 5 and 6)
template <int NB1>
__device__ inline void cell_mm(const bf16* __restrict__ wih,
                               const bf16* __restrict__ whh,
                               const float* __restrict__ xs0,
                               int j, int sub, float (&dg)[4][4])
{
    constexpr int K1 = NB1 * 8;
    constexpr int XS = K1 + 512;
#pragma unroll
    for (int r = 0; r < 4; ++r) {
        const uint4* __restrict__ w1 =
            reinterpret_cast<const uint4*>(wih + (size_t)(j + r * 512) * K1);
#pragma unroll
        for (int g0 = 0; g0 < NB1; g0 += 8) {
            int g = g0 + sub;
            if (g0 + 7 < NB1 || g < NB1) {      // compile-time shaped predicate
                uint4 u = w1[g];
                float a0 = bflo(u.x), a1 = bfhi(u.x), a2 = bflo(u.y), a3 = bfhi(u.y);
                float a4 = bflo(u.z), a5 = bfhi(u.z), a6 = bflo(u.w), a7 = bfhi(u.w);
#pragma unroll
                for (int b = 0; b < 4; ++b) {
                    const float* xp = xs0 + b * XS + g * 8;
                    dg[r][b] += a0 * xp[0] + a1 * xp[1] + a2 * xp[2] + a3 * xp[3]
                              + a4 * xp[4] + a5 * xp[5] + a6 * xp[6] + a7 * xp[7];
                }
            }
        }
        const uint4* __restrict__ w2 =
            reinterpret_cast<const uint4*>(whh + (size_t)(j + r * 512) * 512);
#pragma unroll
        for (int gi = 0; gi < 8; ++gi) {
            int g = gi * 8 + sub;
            uint4 u = w2[g];
            float a0 = bflo(u.x), a1 = bfhi(u.x), a2 = bflo(u.y), a3 = bfhi(u.y);
            float a4 = bflo(u.z), a5 = bfhi(u.z), a6 = bflo(u.w), a7 = bfhi(u.w);
#pragma unroll
            for (int b = 0; b < 4; ++b) {
                const float* xp = xs0 + b * XS + K1 + g * 8;
                dg[r][b] += a0 * xp[0] + a1 * xp[1] + a2 * xp[2] + a3 * xp[3]
                          + a4 * xp[4] + a5 * xp[5] + a6 * xp[6] + a7 * xp[7];
            }
        }
    }
}

// one LSTM cell (l,t) on 16 blocks x 256 thr; plain cached loads (dispatch
// boundaries provide cross-XCD coherence -- no atomics, no flags).
template <int NB1>
__device__ inline void cell_step(
    int l, int t, int bx,
    const bf16* __restrict__ wih, const bf16* __restrict__ whh,
    const float* __restrict__ bih, const float* __restrict__ bhh,
    const float* __restrict__ states,
    const float* __restrict__ featm, const float* __restrict__ feats,
    float* __restrict__ hAll, float* __restrict__ cst,
    float* __restrict__ xs)
{
    constexpr int K1 = NB1 * 8;
    constexpr int XS = K1 + 512;
    const int tid = threadIdx.x;
    const int jloc = tid >> 3;           // 0..31
    const int sub = tid & 7;             // 0..7
    const int j = bx * 32 + jloc;

    const float* hprev = (l == 0) ? nullptr
                       : hAll + ((size_t)(t + 1) * 6 + (l - 1)) * 2048;
    const float* hold  = hAll + ((size_t)t * 6 + l) * 2048;
    float* hnew        = hAll + ((size_t)(t + 1) * 6 + l) * 2048;

    if (NB1 == 72) {
        // per b: [0,512)=hprev, [512,576)=feat, [576,1088)=hold
        for (int i = tid; i < 4 * 512; i += 256) {
            int bb = i >> 9, kk = i & 511;      // float2 pair index
            float2 cv;
            int base;
            if (kk < 256) {
                cv = *reinterpret_cast<const float2*>(&hprev[bb * 512 + kk * 2]);
                base = bb * XS + kk * 2;
            } else {
                cv = *reinterpret_cast<const float2*>(&hold[bb * 512 + (kk - 256) * 2]);
                base = bb * XS + 576 + (kk - 256) * 2;
            }
            xs[base] = cv.x; xs[base + 1] = cv.y;
        }
        {
            int bb = tid >> 6, k = tid & 63;
            xs[bb * XS + 512 + k] = imgfeat(featm, feats, bb, t, k);
        }
    } else {
        // per b: [0,6)=states, [6,70)=feat, [70,72)=0, [72,584)=hold
        for (int i = tid; i < 4 * 256; i += 256) {
            int bb = i >> 8, kk = i & 255;
            float2 cv = *reinterpret_cast<const float2*>(&hold[bb * 512 + kk * 2]);
            int base = bb * XS + 72 + kk * 2;
            xs[base] = cv.x; xs[base + 1] = cv.y;
        }
        for (int i = tid; i < 4 * 72; i += 256) {
            int bb = i / 72, k = i - bb * 72;
            float v = (k < 6) ? states[(bb * 10 + t) * 6 + k]
                              : (k < 70 ? imgfeat(featm, feats, bb, t, k - 6) : 0.f);
            xs[bb * XS + k] = v;
        }
    }
    __syncthreads();

    float dg[4][4] = {{0.f, 0.f, 0.f, 0.f}, {0.f, 0.f, 0.f, 0.f},
                      {0.f, 0.f, 0.f, 0.f}, {0.f, 0.f, 0.f, 0.f}};
    cell_mm<NB1>(wih, whh, xs, j, sub, dg);

#pragma unroll
    for (int r = 0; r < 4; ++r)
#pragma unroll
        for (int b = 0; b < 4; ++b) {
            dg[r][b] += __shfl_xor(dg[r][b], 1);
            dg[r][b] += __shfl_xor(dg[r][b], 2);
            dg[r][b] += __shfl_xor(dg[r][b], 4);
        }

    if (sub == 0) {
        float b0 = bih[j] + bhh[j];
        float b1 = bih[j + 512] + bhh[j + 512];
        float b2 = bih[j + 1024] + bhh[j + 1024];
        float b3 = bih[j + 1536] + bhh[j + 1536];
#pragma unroll
        for (int b = 0; b < 4; ++b) {
            float gi = dg[0][b] + b0;
            float gf = dg[1][b] + b1;
            float gg = dg[2][b] + b2;
            float go = dg[3][b] + b3;
            float cp = cst[b * 512 + j];
            float c2 = sigmoidf_(gf) * cp + sigmoidf_(gi) * tanhf(gg);
            float h2 = sigmoidf_(go) * tanhf(c2);
            cst[b * 512 + j] = c2;
            hnew[b * 512 + j] = h2;
        }
    }
}

// ---------------- LSTM: one dispatch per anti-diagonal ----------------------
// grid = dim3(16, 7): y = layer slot (6 = out projection), x = gate block.
// Dispatch boundary = HW-optimized cross-XCD sync. R2-R7 established: every
// intra-kernel handoff protocol (acquire, relaxed, per-block flags, LLC RMW)
// costs ~20us/hop on this chip -- same as a dispatch. Dispatches are simpler.
__global__ __launch_bounds__(256) void lstm_diag2_k(
    const bf16* __restrict__ wih0p, const bf16* __restrict__ whh0b,
    const bf16* __restrict__ wihrb, const bf16* __restrict__ whhrb,
    const float* __restrict__ bih0, const float* __restrict__ bhh0,
    const float* __restrict__ bihr, const float* __restrict__ bhhr,
    const float* __restrict__ states,
    const float* __restrict__ featm, const float* __restrict__ feats,
    float* __restrict__ hAll, float* __restrict__ cAll,
    const float* __restrict__ out_w, const float* __restrict__ out_b,
    float* __restrict__ out, int d)
{
    const int l = blockIdx.y;
    const int bx = blockIdx.x;
    const int tid = threadIdx.x;
    __shared__ float xs[4 * 1088];

    if (l == 6) {                       // out projection for t = d-6
        int t = d - 6;
        if (t < 0 || t >= 10 || bx != 0) return;
        const float* h5 = hAll + ((size_t)(t + 1) * 6 + 5) * 2048;
        int p = tid >> 3, sub = tid & 7;
        if (p >= 24) return;
        int b = p / 6, a = p % 6;
        const float* wr = out_w + a * 576;
        float acc = 0.f;
        for (int k = sub; k < 256; k += 8) {
            float2 cv = *reinterpret_cast<const float2*>(&h5[b * 512 + k * 2]);
            acc += wr[k * 2] * cv.x + wr[k * 2 + 1] * cv.y;
        }
        for (int k = sub; k < 64; k += 8)
            acc += wr[512 + k] * imgfeat(featm, feats, b, t, k);
        acc += __shfl_xor(acc, 1);
        acc += __shfl_xor(acc, 2);
        acc += __shfl_xor(acc, 4);
        if (sub == 0) out[(b * 10 + t) * 6 + a] = acc + out_b[a];
        return;
    }

    const int t = d - l;
    if (t < 0 || t >= 10) return;

    float* cst = cAll + (size_t)l * 2048;
    if (l == 0) {
        cell_step<9>(0, t, bx, wih0p, whh0b, bih0, bhh0,
                     states, featm, feats, hAll, cst, xs);
    } else {
        const bf16* wih = wihrb + (size_t)(l - 1) * 2048 * 576;
        const bf16* whh = whhrb + (size_t)(l - 1) * 2048 * 512;
        const float* bih = bihr + (l - 1) * 2048;
        const float* bhh = bhhr + (l - 1) * 2048;
        cell_step<72>(l, t, bx, wih, whh, bih, bhh,
                      states, featm, feats, hAll, cst, xs);
    }
}

// ---------------- host orchestration ----------------------------------------
extern "C" void kernel_launch(void* const* d_in, const int* in_sizes, int n_in,
                              void* d_out, int out_size, void* d_ws, size_t ws_size,
                              hipStream_t stream)
{
    const float* seq_m = (const float*)d_in[0];
    const float* seq_s = (const float*)d_in[1];
    const float* states = (const float*)d_in[2];
    const float *cw[2][4], *cb[2][4];
    for (int cam = 0; cam < 2; ++cam)
        for (int j = 0; j < 4; ++j) {
            cw[cam][j] = (const float*)d_in[3 + cam * 8 + j * 2];
            cb[cam][j] = (const float*)d_in[3 + cam * 8 + j * 2 + 1];
        }
    const float* wih0  = (const float*)d_in[19];
    const float* whh0  = (const float*)d_in[20];
    const float* bih0  = (const float*)d_in[21];
    const float* bhh0  = (const float*)d_in[22];
    const float* wih_r = (const float*)d_in[23];
    const float* whh_r = (const float*)d_in[24];
    const float* bih_r = (const float*)d_in[25];
    const float* bhh_r = (const float*)d_in[26];
    const float* out_w = (const float*)d_in[27];
    const float* out_b = (const float*)d_in[28];
    float* out = (float*)d_out;

    // ---- workspace carve (256B-aligned) ----
    char* wsc = (char*)d_ws;
    auto carve = [&](size_t bytes) {
        char* p = wsc;
        wsc += (bytes + 255) & ~(size_t)255;
        return p;
    };
    float* featm = (float*)carve(40 * 32 * 4);
    float* feats = (float*)carve(40 * 32 * 4);
    float* hAll  = (float*)carve((size_t)11 * 6 * 2048 * 4);
    float* cAll  = (float*)carve((size_t)6 * 2048 * 4);
    char*  zpage = carve(8192);
    float* partial = (float*)carve((size_t)80 * 16 * 256 * 4 * 4);
    const int wtElts[4] = {3072, 18432, 73728, 18432};
    bf16* wT[2][4];
    for (int cam = 0; cam < 2; ++cam)
        for (int j = 0; j < 4; ++j) wT[cam][j] = (bf16*)carve(wtElts[j] * 2);
    bf16* wih0p = (bf16*)carve((size_t)2048 * 72 * 2);
    bf16* whh0b = (bf16*)carve((size_t)2048 * 512 * 2);
    bf16* wihrb = (bf16*)carve((size_t)5 * 2048 * 576 * 2);
    bf16* whhrb = (bf16*)carve((size_t)5 * 2048 * 512 * 2);

    size_t used = (size_t)(wsc - (char*)d_ws);
    size_t rem = ws_size > used ? ws_size - used : 0;
    int CHI = 1;
    const int cands[8] = {40, 20, 10, 8, 5, 4, 2, 1};
    for (int i = 0; i < 8; ++i) {
        size_t need = (size_t)2 * cands[i] * (128 + 64) * HWPX * 2;
        if (need <= rem) { CHI = cands[i]; break; }
    }
    bf16* bufA = (bf16*)carve((size_t)2 * CHI * HWPX * 128 * 2);
    bf16* bufB = (bf16*)carve((size_t)2 * CHI * HWPX * 64 * 2);

    hipMemsetAsync(hAll, 0, 6 * 2048 * 4, stream);       // t=-1 slot
    hipMemsetAsync(cAll, 0, 6 * 2048 * 4, stream);
    hipMemsetAsync(zpage, 0, 8192, stream);

    // ---- weight preps ----
    prep_lstm_k<<<2048, 256, 0, stream>>>(wih0, whh0, wih_r, whh_r,
                                          wih0p, whh0b, wihrb, whhrb);
    ConvW cwArg;
    for (int cam = 0; cam < 2; ++cam)
        for (int j = 0; j < 4; ++j) {
            cwArg.src[cam * 4 + j] = cw[cam][j];
            cwArg.dst[cam * 4 + j] = wT[cam][j];
        }
    prep_conv_k<<<888, 256, 0, stream>>>(cwArg);

    // ---- CNN + fused spatial softmax (both cams per dispatch) ----
    for (int c0 = 0; c0 < 40; c0 += CHI) {
        int ch = (40 - c0) < CHI ? (40 - c0) : CHI;
        conv01<<<dim3(128, 2, ch), 256, 0, stream>>>(
            seq_m, seq_s, wT[0][0], wT[1][0], cb[0][0], cb[1][0],
            wT[0][1], wT[1][1], cb[0][1], cb[1][1], bufB, c0);
        conv2r<64, 128><<<dim3(128, 2, ch), 256, 0, stream>>>(
            bufB, wT[0][2], wT[1][2], cb[0][2], cb[1][2], bufA, zpage);
        conv4_xs<<<dim3(256, 2, ch), 256, 0, stream>>>(
            bufA, wT[0][3], wT[1][3], cb[0][3], cb[1][3], partial, zpage, c0);
    }
    ssmerge_k<<<80, 256, 0, stream>>>(partial, featm, feats);

    // ---- LSTM wavefront: 16 small dispatches (112 blocks each) -------------
    for (int d = 0; d < 16; ++d) {
        lstm_diag2_k<<<dim3(16, 7), 256, 0, stream>>>(
            wih0p, whh0b, wihrb, whhrb, bih0, bhh0, bih_r, bhh_r,
            states, featm, feats, hAll, cAll, out_w, out_b, out, d);
    }
}

// Round 9
// 1113.388 us; speedup vs baseline: 1.0960x; 1.0163x over previous
//
#include <hip/hip_runtime.h>
#include <hip/hip_bf16.h>
#include <math.h>

typedef __hip_bfloat16 bf16;
typedef short bf16x8 __attribute__((ext_vector_type(8)));
typedef float f32x4 __attribute__((ext_vector_type(4)));

static constexpr int HWPX = 16384;   // 128*128

__device__ inline float sigmoidf_(float x) { return 1.0f / (1.0f + expf(-x)); }
__device__ inline float bflo(unsigned u) { return __uint_as_float(u << 16); }
__device__ inline float bfhi(unsigned u) { return __uint_as_float(u & 0xffff0000u); }
__device__ inline int swz(int x) { return (x ^ (x >> 2)) & 3; }

// async global->LDS, 16B per lane; lds base wave-uniform (lane i -> +i*16)
__device__ inline void gll16(const bf16* g, short* l) {
    __builtin_amdgcn_global_load_lds(
        (const __attribute__((address_space(1))) void*)g,
        (__attribute__((address_space(3))) void*)l, 16, 0, 0);
}

// ---------------- prep: LSTM weights -> bf16 (wih0 padded 70->72) -----------
__global__ __launch_bounds__(256) void prep_lstm_k(
    const float* __restrict__ wih0, const float* __restrict__ whh0,
    const float* __restrict__ wihr, const float* __restrict__ whhr,
    bf16* __restrict__ d0, bf16* __restrict__ d1,
    bf16* __restrict__ d2, bf16* __restrict__ d3)
{
    const size_t nA = 2048ull * 72, nB = 2048ull * 512;
    const size_t nC = 5ull * 2048 * 576, nD = 5ull * 2048 * 512;
    for (size_t i = blockIdx.x * 256ull + threadIdx.x; i < nA + nB + nC + nD;
         i += (size_t)gridDim.x * 256) {
        if (i < nA) {
            int c = (int)(i % 72), r = (int)(i / 72);
            d0[i] = __float2bfloat16(c < 70 ? wih0[(size_t)r * 70 + c] : 0.f);
        } else if (i < nA + nB) {
            size_t k = i - nA; d1[k] = __float2bfloat16(whh0[k]);
        } else if (i < nA + nB + nC) {
            size_t k = i - nA - nB; d2[k] = __float2bfloat16(wihr[k]);
        } else {
            size_t k = i - nA - nB - nC; d3[k] = __float2bfloat16(whhr[k]);
        }
    }
}

// ---------------- prep: conv weights, both cams -----------------------------
struct ConvW {
    const float* src[8];
    bf16* dst[8];
};

__global__ __launch_bounds__(256) void prep_conv_k(ConvW a)
{
    const int sizes[4] = {3072, 18432, 73728, 18432};
    const int cins[4] = {3, 32, 64, 128};
    const int couts[4] = {32, 64, 128, 16};
    int total = 2 * 113664;
    for (int idx = blockIdx.x * 256 + threadIdx.x; idx < total; idx += gridDim.x * 256) {
        int i = idx, cam = 0;
        if (i >= 113664) { cam = 1; i -= 113664; }
        int layer = 0;
        while (layer < 3 && i >= sizes[layer]) { i -= sizes[layer]; ++layer; }
        const float* w = a.src[cam * 4 + layer];
        bf16* d = a.dst[cam * 4 + layer];
        if (layer == 0) {
            // [3ky][32co][32k], k = kx*8 + c
            int k = i & 31, co = (i >> 5) & 31, ky = i >> 10;
            int kx = k >> 3, c = k & 7;
            float v = (kx < 3 && c < 3) ? w[((co * 3 + c) * 3 + ky) * 3 + kx] : 0.f;
            d[i] = __float2bfloat16(v);
        } else {
            // dst [tap][kc][q][co][8]
            int CIN = cins[layer], COUT = couts[layer], KC = CIN / 32;
            int e = i & 7;
            int t2 = i >> 3;
            int co = t2 % COUT;
            int t3 = t2 / COUT;
            int q = t3 & 3;
            int t4 = t3 >> 2;
            int kc = t4 % KC;
            int tap = t4 / KC;
            d[i] = __float2bfloat16(w[((size_t)(co * CIN + kc * 32 + q * 8 + e)) * 9 + tap]);
        }
    }
}

// ---------------- fused conv0+conv1: raw fp32 -> 64ch bf16 ------------------
__global__ __launch_bounds__(256, 4) void conv01(
    const float* __restrict__ srcm, const float* __restrict__ srcs,
    const bf16* __restrict__ w0m, const bf16* __restrict__ w0s,
    const float* __restrict__ b0m, const float* __restrict__ b0s,
    const bf16* __restrict__ wTm, const bf16* __restrict__ wTs,
    const float* __restrict__ bm, const float* __restrict__ bs,
    bf16* __restrict__ out, int c0)
{
    constexpr int COUT = 64, MW = 2;          // conv1: 32 -> 64
    constexpr int SLOTS = 4 * 264;            // 4 rows x 66 px x 4 granules

    const int y0 = (blockIdx.x >> 1) * 2;
    const int x0 = (blockIdx.x & 1) * 64;
    const int cam = blockIdx.y;
    const int img = blockIdx.z;
    const int ci_ = cam * gridDim.z + img;
    const float* inImg = (cam ? srcs : srcm) + (size_t)(c0 + img) * 3 * HWPX;
    const bf16* wT0 = cam ? w0s : w0m;
    const float* bias0 = cam ? b0s : b0m;
    const bf16* wT = cam ? wTs : wTm;
    const float* bias = cam ? bs : bm;
    const int tid = threadIdx.x;
    const int wave = tid >> 6, lane = tid & 63;
    const int wrow = wave >> 1, wm = wave & 1;
    const int q = lane >> 4, n16 = lane & 15;

    __shared__ short smem[SLOTS * 8];         // conv0 out / conv1 in
    __shared__ short raw[6 * 68 * 16];        // conv0 input fragments

    // zero conv0-out region (border rows/px stay zero = SAME padding)
    for (int i = tid; i < SLOTS; i += 256)
        *(bf16x8*)(void*)&smem[i * 8] = (bf16x8)0;

    // stage raw halo: rows y0-2..y0+3, px x0-2..x0+65, 3 channels
    for (int d = tid; d < 6 * 68; d += 256) {
        int x = d % 68, r = d / 68;
        int yy = y0 - 2 + r, xx = x0 - 2 + x;
        bf16 v8[8];
#pragma unroll
        for (int c = 0; c < 8; ++c) v8[c] = __float2bfloat16(0.f);
        if ((unsigned)yy < 128u && (unsigned)xx < 128u) {
            int o = yy * 128 + xx;
            v8[0] = __float2bfloat16(inImg[o]);
            v8[1] = __float2bfloat16(inImg[HWPX + o]);
            v8[2] = __float2bfloat16(inImg[2 * HWPX + o]);
        }
        *(bf16x8*)(void*)&raw[d * 16] = *(bf16x8*)(void*)v8;
        *(bf16x8*)(void*)&raw[d * 16 + 8] = (bf16x8)0;
    }
    __syncthreads();

    // conv0 MFMA: rows rp=0..3 (global y0-1+rp), px xt (global x0-1+xt)
    const int co0_ = wm * 16 + n16;
    for (int rp = 0; rp < 4; ++rp) {
        int Y = y0 - 1 + rp;
        if ((unsigned)Y >= 128u) continue;     // wave-uniform; stays zero
        for (int xg = wrow; xg < 5; xg += 2) { // waves split px-groups
            int xt = xg * 16 + n16;
            int xts = xt < 66 ? xt : 65;       // clamp to keep LDS reads legal
            f32x4 a0 = f32x4{0.f, 0.f, 0.f, 0.f};
#pragma unroll
            for (int ky = 0; ky < 3; ++ky) {
                bf16x8 aF = *(const bf16x8*)(const void*)(wT0 +
                    ((size_t)(ky * 32 + co0_) * 32) + q * 8);
                int off = (q < 3) ? ((rp + ky) * 68 + xts + q) * 16
                                  : ((rp + ky) * 68 + xts) * 16 + 8;
                bf16x8 bF = *(const bf16x8*)(const void*)&raw[off];
                a0 = __builtin_amdgcn_mfma_f32_16x16x32_bf16(aF, bF, a0, 0, 0, 0);
            }
            int X = x0 - 1 + xt;
            if (xt < 66 && (unsigned)X < 128u) {
                int cb0 = wm * 16 + q * 4;
                bf16 tmp[4];
#pragma unroll
                for (int r = 0; r < 4; ++r) {
                    float v = a0[r] + bias0[cb0 + r];
                    tmp[r] = __float2bfloat16(v > 0.f ? v : 0.f);
                }
                int g = cb0 >> 3;                       // granule 0..3
                int sbase = (rp * 264 + xt * 4 + (g ^ swz(xt))) * 8 + (q & 1) * 4;
                *reinterpret_cast<uint2*>(&smem[sbase]) = *reinterpret_cast<uint2*>(tmp);
            }
        }
    }
    __syncthreads();

    // conv1 compute (identical to conv2r<32,64> inner loop, KC=1)
    f32x4 acc[MW][4];
#pragma unroll
    for (int mt = 0; mt < MW; ++mt)
#pragma unroll
        for (int nt = 0; nt < 4; ++nt) acc[mt][nt] = f32x4{0.f, 0.f, 0.f, 0.f};

#pragma unroll
    for (int ky = 0; ky < 3; ++ky) {
#pragma unroll
        for (int kx = 0; kx < 3; ++kx) {
            bf16x8 aF[MW];
#pragma unroll
            for (int mt = 0; mt < MW; ++mt) {
                int co = (wm * MW + mt) * 16 + n16;
                aF[mt] = *(const bf16x8*)(const void*)(wT +
                    (((size_t)(ky * 3 + kx) * 4 + q) * COUT + co) * 8);
            }
#pragma unroll
            for (int nt = 0; nt < 4; ++nt) {
                int xt = nt * 16 + n16 + kx;           // 0..65
                int slot = (wrow + ky) * 264 + xt * 4 + (q ^ swz(xt));
                bf16x8 bF = *(const bf16x8*)(const void*)&smem[slot * 8];
#pragma unroll
                for (int mt = 0; mt < MW; ++mt)
                    acc[mt][nt] = __builtin_amdgcn_mfma_f32_16x16x32_bf16(
                        aF[mt], bF, acc[mt][nt], 0, 0, 0);
            }
        }
    }

    const int y = y0 + wrow;
#pragma unroll
    for (int mt = 0; mt < MW; ++mt) {
        int co0 = (wm * MW + mt) * 16 + q * 4;
#pragma unroll
        for (int nt = 0; nt < 4; ++nt) {
            int x = x0 + nt * 16 + n16;
            bf16 tmp[4];
#pragma unroll
            for (int r = 0; r < 4; ++r) {
                float v = acc[mt][nt][r] + bias[co0 + r];
                tmp[r] = __float2bfloat16(v > 0.f ? v : 0.f);
            }
            *reinterpret_cast<uint2*>(out + ((size_t)ci_ * HWPX + y * 128 + x) * COUT + co0)
                = *reinterpret_cast<uint2*>(tmp);
        }
    }
}

// ---------------- mid convs: 2 rows x 64px per block, gll dbuf --------------
template <int CIN, int COUT>
__global__ __launch_bounds__(256, 4) void conv2r(
    const bf16* __restrict__ in, const bf16* __restrict__ wTm,
    const bf16* __restrict__ wTs, const float* __restrict__ bm,
    const float* __restrict__ bs, bf16* __restrict__ out,
    const char* __restrict__ zpage)
{
    constexpr int KC = CIN / 32;
    constexpr int NB = (KC > 1) ? 2 : 1;
    constexpr int MW = COUT / 32;       // co tiles per wave (2 co-halves)
    constexpr int SLOTS = 4 * 264;      // 4 rows x 66 x x 4 granules

    const int y0 = (blockIdx.x >> 1) * 2;
    const int x0 = (blockIdx.x & 1) * 64;
    const int cam = blockIdx.y;
    const int img = blockIdx.z;
    const int ci_ = cam * gridDim.z + img;
    const bf16* wT = cam ? wTs : wTm;
    const float* bias = cam ? bs : bm;
    const int tid = threadIdx.x;
    const int wave = tid >> 6, lane = tid & 63;
    const int wrow = wave >> 1, wm = wave & 1;
    const int q = lane >> 4, n16 = lane & 15;

    __shared__ short smem[NB][SLOTS * 8];
    const bf16* inImg = in + (size_t)ci_ * HWPX * CIN;

    const bf16* sptr[5];
#pragma unroll
    for (int it = 0; it < 5; ++it) {
        int s = it * 256 + tid;
        int r = s / 264, s2 = s - r * 264;
        int sx = s2 >> 2;
        int g = (s2 & 3) ^ swz(sx);
        int yy = y0 + r - 1, xx = x0 + sx - 1;
        bool ok = (s < SLOTS) && ((unsigned)yy < 128u) && ((unsigned)xx < 128u);
        sptr[it] = ok ? inImg + ((size_t)yy * 128 + xx) * CIN + g * 8
                      : (const bf16*)(zpage + (tid & 255) * 16);
    }
    auto stage = [&](int kc, int buf) {
#pragma unroll
        for (int it = 0; it < 5; ++it) {
            if (it * 256 + tid < SLOTS)
                gll16(sptr[it] + kc * 32, &smem[buf][it * 2048 + wave * 512]);
        }
    };

    f32x4 acc[MW][4];
#pragma unroll
    for (int mt = 0; mt < MW; ++mt)
#pragma unroll
        for (int nt = 0; nt < 4; ++nt) acc[mt][nt] = f32x4{0.f, 0.f, 0.f, 0.f};

    stage(0, 0);
    for (int kc = 0; kc < KC; ++kc) {
        __syncthreads();
        if (kc + 1 < KC) stage(kc + 1, (kc + 1) % NB);
        const short* sb = smem[kc % NB];
#pragma unroll
        for (int ky = 0; ky < 3; ++ky) {
#pragma unroll
            for (int kx = 0; kx < 3; ++kx) {
                bf16x8 aF[MW];
#pragma unroll
                for (int mt = 0; mt < MW; ++mt) {
                    int co = (wm * MW + mt) * 16 + n16;
                    aF[mt] = *(const bf16x8*)(const void*)(wT +
                        ((((size_t)(ky * 3 + kx) * KC + kc) * 4 + q) * COUT + co) * 8);
                }
#pragma unroll
                for (int nt = 0; nt < 4; ++nt) {
                    int xt = nt * 16 + n16 + kx;           // 0..65
                    int slot = (wrow + ky) * 264 + xt * 4 + (q ^ swz(xt));
                    bf16x8 bF = *(const bf16x8*)(const void*)&sb[slot * 8];
#pragma unroll
                    for (int mt = 0; mt < MW; ++mt)
                        acc[mt][nt] = __builtin_amdgcn_mfma_f32_16x16x32_bf16(
                            aF[mt], bF, acc[mt][nt], 0, 0, 0);
                }
            }
        }
    }

    const int y = y0 + wrow;
#pragma unroll
    for (int mt = 0; mt < MW; ++mt) {
        int co0 = (wm * MW + mt) * 16 + q * 4;
#pragma unroll
        for (int nt = 0; nt < 4; ++nt) {
            int x = x0 + nt * 16 + n16;
            bf16 tmp[4];
#pragma unroll
            for (int r = 0; r < 4; ++r) {
                float v = acc[mt][nt][r] + bias[co0 + r];
                tmp[r] = __float2bfloat16(v > 0.f ? v : 0.f);
            }
            *reinterpret_cast<uint2*>(out + ((size_t)ci_ * HWPX + y * 128 + x) * COUT + co0)
                = *reinterpret_cast<uint2*>(tmp);
        }
    }
}

// ---------------- conv4 (128->16): 4 rows x 64px per block ------------------
// R8 ledger + R5 FETCH evidence: 1-row blocks re-fetch the 3-row halo with
// ~1.65x amplification. 4-row blocks stage 6 rows per 4 outputs (1.5x ideal),
// and each weight fragment feeds 4 MFMAs. Slot/swizzle layout identical to
// the proven conv4_xs; row index within LDS is rp+ky.
__global__ __launch_bounds__(256, 2) void conv4_r4(
    const bf16* __restrict__ in, const bf16* __restrict__ wTm,
    const bf16* __restrict__ wTs, const float* __restrict__ bm,
    const float* __restrict__ bs,
    float* __restrict__ partial,   // [gimg][16][256] x {M,S,SX,-}
    const char* __restrict__ zpage, int c0)
{
    constexpr int CIN = 128, KC = 4;
    constexpr int RR = 4;                  // output rows per block
    constexpr int SLOTS = (RR + 2) * 264;  // 6 rows x 66 px x 4 granules = 1584
    const int y0 = (blockIdx.x >> 1) * RR;
    const int xh = blockIdx.x & 1;
    const int x0 = xh * 64;
    const int cam = blockIdx.y;
    const int img = blockIdx.z;
    const int ci_ = cam * gridDim.z + img;
    const int gimg = cam * 40 + c0 + img;
    const bf16* wT = cam ? wTs : wTm;
    const float* bias = cam ? bs : bm;
    const int tid = threadIdx.x;
    const int wave = tid >> 6, lane = tid & 63;
    const int q = lane >> 4, n16 = lane & 15;

    __shared__ short smem[2][SLOTS * 8];
    __shared__ float sred[3][RR][4][16];
    const bf16* inImg = in + (size_t)ci_ * HWPX * CIN;

    const bf16* sptr[7];
#pragma unroll
    for (int it = 0; it < 7; ++it) {
        int s = it * 256 + tid;
        int r = s / 264, s2 = s - r * 264;
        int sx = s2 >> 2;
        int g = (s2 & 3) ^ swz(sx);
        int yy = y0 + r - 1, xx = x0 + sx - 1;
        bool ok = (s < SLOTS) && ((unsigned)yy < 128u) && ((unsigned)xx < 128u);
        sptr[it] = ok ? inImg + ((size_t)yy * 128 + xx) * CIN + g * 8
                      : (const bf16*)(zpage + (tid & 255) * 16);
    }
    auto stage = [&](int kc, int buf) {
#pragma unroll
        for (int it = 0; it < 7; ++it) {
            if (it * 256 + tid < SLOTS)
                gll16(sptr[it] + kc * 32, &smem[buf][it * 2048 + wave * 512]);
        }
    };

    f32x4 acc[RR];
#pragma unroll
    for (int rp = 0; rp < RR; ++rp) acc[rp] = f32x4{0.f, 0.f, 0.f, 0.f};

    stage(0, 0);
    for (int kc = 0; kc < KC; ++kc) {
        __syncthreads();
        if (kc + 1 < KC) stage(kc + 1, (kc + 1) & 1);
        const short* sb = smem[kc & 1];
#pragma unroll
        for (int ky = 0; ky < 3; ++ky) {
#pragma unroll
            for (int kx = 0; kx < 3; ++kx) {
                bf16x8 aF = *(const bf16x8*)(const void*)(wT +
                    ((((size_t)(ky * 3 + kx) * KC + kc) * 4 + q) * 16 + n16) * 8);
                int xt = wave * 16 + n16 + kx;
                int sbase = xt * 4 + (q ^ swz(xt));
#pragma unroll
                for (int rp = 0; rp < RR; ++rp) {
                    bf16x8 bF = *(const bf16x8*)(const void*)
                        &sb[((rp + ky) * 264 + sbase) * 8];
                    acc[rp] = __builtin_amdgcn_mfma_f32_16x16x32_bf16(
                        aF, bF, acc[rp], 0, 0, 0);
                }
            }
        }
    }

    // bias + relu; online partials per row over this 64px half-row
    int x = x0 + wave * 16 + n16;
    float px = -1.f + (2.f / 127.f) * x;
    float v[RR][4], M[RR][4];
#pragma unroll
    for (int rp = 0; rp < RR; ++rp)
#pragma unroll
        for (int r = 0; r < 4; ++r) {
            float t = acc[rp][r] + bias[q * 4 + r];
            v[rp][r] = t > 0.f ? t : 0.f;
            M[rp][r] = v[rp][r];
        }
#pragma unroll
    for (int rp = 0; rp < RR; ++rp)
#pragma unroll
        for (int r = 0; r < 4; ++r) {
            M[rp][r] = fmaxf(M[rp][r], __shfl_xor(M[rp][r], 1));
            M[rp][r] = fmaxf(M[rp][r], __shfl_xor(M[rp][r], 2));
            M[rp][r] = fmaxf(M[rp][r], __shfl_xor(M[rp][r], 4));
            M[rp][r] = fmaxf(M[rp][r], __shfl_xor(M[rp][r], 8));
        }
    if (n16 == 0)
#pragma unroll
        for (int rp = 0; rp < RR; ++rp)
#pragma unroll
            for (int r = 0; r < 4; ++r) sred[0][rp][wave][q * 4 + r] = M[rp][r];
    __syncthreads();
#pragma unroll
    for (int rp = 0; rp < RR; ++rp)
#pragma unroll
        for (int r = 0; r < 4; ++r) {
            M[rp][r] = fmaxf(fmaxf(sred[0][rp][0][q * 4 + r], sred[0][rp][1][q * 4 + r]),
                             fmaxf(sred[0][rp][2][q * 4 + r], sred[0][rp][3][q * 4 + r]));
        }
    float s[RR][4], sx[RR][4];
#pragma unroll
    for (int rp = 0; rp < RR; ++rp)
#pragma unroll
        for (int r = 0; r < 4; ++r) {
            float e = expf(v[rp][r] - M[rp][r]);
            s[rp][r] = e; sx[rp][r] = e * px;
            s[rp][r] += __shfl_xor(s[rp][r], 1);  sx[rp][r] += __shfl_xor(sx[rp][r], 1);
            s[rp][r] += __shfl_xor(s[rp][r], 2);  sx[rp][r] += __shfl_xor(sx[rp][r], 2);
            s[rp][r] += __shfl_xor(s[rp][r], 4);  sx[rp][r] += __shfl_xor(sx[rp][r], 4);
            s[rp][r] += __shfl_xor(s[rp][r], 8);  sx[rp][r] += __shfl_xor(sx[rp][r], 8);
        }
    __syncthreads();
    if (n16 == 0)
#pragma unroll
        for (int rp = 0; rp < RR; ++rp)
#pragma unroll
            for (int r = 0; r < 4; ++r) {
                sred[1][rp][wave][q * 4 + r] = s[rp][r];
                sred[2][rp][wave][q * 4 + r] = sx[rp][r];
            }
    __syncthreads();
    if (tid < 16 * RR) {
        int rp = tid >> 4, c = tid & 15;
        float S = sred[1][rp][0][c] + sred[1][rp][1][c] + sred[1][rp][2][c] + sred[1][rp][3][c];
        float SX = sred[2][rp][0][c] + sred[2][rp][1][c] + sred[2][rp][2][c] + sred[2][rp][3][c];
        float Mv = fmaxf(fmaxf(sred[0][rp][0][c], sred[0][rp][1][c]),
                         fmaxf(sred[0][rp][2][c], sred[0][rp][3][c]));
        float* pp = partial + (((size_t)gimg * 16 + c) * 256 + ((y0 + rp) * 2 + xh)) * 4;
        pp[0] = Mv; pp[1] = S; pp[2] = SX;
    }
}

// ---------------- merge partials -> (ex, ey), both cams ---------------------
__global__ __launch_bounds__(256) void ssmerge_k(
    const float* __restrict__ partial, float* __restrict__ featm,
    float* __restrict__ feats)
{
    const int img = blockIdx.x;          // 0..79
    const int cam = img / 40, li = img % 40;
    float* feat = cam ? feats : featm;
    const int tid = threadIdx.x;
    const int co = tid >> 4, s = tid & 15;
    const float* base = partial + ((size_t)img * 16 + co) * 256 * 4;
    float M = -1e30f, S = 0.f, SX = 0.f, SY = 0.f;
    for (int i = s; i < 256; i += 16) {
        float m = base[i * 4], sv = base[i * 4 + 1], sxv = base[i * 4 + 2];
        float py = -1.f + (2.f / 127.f) * (i >> 1);
        float Mn = fmaxf(M, m);
        float w0 = expf(M - Mn), w1 = expf(m - Mn);
        S = S * w0 + sv * w1;
        SX = SX * w0 + sxv * w1;
        SY = SY * w0 + sv * py * w1;
        M = Mn;
    }
#pragma unroll
    for (int mask = 1; mask < 16; mask <<= 1) {
        float Mo = __shfl_xor(M, mask), So = __shfl_xor(S, mask);
        float SXo = __shfl_xor(SX, mask), SYo = __shfl_xor(SY, mask);
        float Mn = fmaxf(M, Mo);
        float w0 = expf(M - Mn), w1 = expf(Mo - Mn);
        S = S * w0 + So * w1; SX = SX * w0 + SXo * w1; SY = SY * w0 + SYo * w1;
        M = Mn;
    }
    if (s == 0) {
        feat[(size_t)li * 32 + 2 * co] = SX / S;
        feat[(size_t)li * 32 + 2 * co + 1] = SY / S;
    }
}

// ---------------- LSTM helpers ----------------------------------------------
__device__ inline float imgfeat(const float* featm, const float* feats,
                                int b, int t, int k)
{
    int idx = (b * 10 + t) * 32;
    return k < 32 ? featm[idx + k] : feats[idx + k - 32];
}

// per-thread GEMV slice: 32-gate block, all 4 batches folded into the thread.
// NB1 = K1/8 (compile-time) -> fully unrolled, pipelined weight loads.
// (verified correct in rounds 5-8)
template <int NB1>
__device__ inline void cell_mm(const bf16* __restrict__ wih,
                               const bf16* __restrict__ whh,
                               const float* __restrict__ xs0,
                               int j, int sub, float (&dg)[4][4])
{
    constexpr int K1 = NB1 * 8;
    constexpr int XS = K1 + 512;
#pragma unroll
    for (int r = 0; r < 4; ++r) {
        const uint4* __restrict__ w1 =
            reinterpret_cast<const uint4*>(wih + (size_t)(j + r * 512) * K1);
#pragma unroll
        for (int g0 = 0; g0 < NB1; g0 += 8) {
            int g = g0 + sub;
            if (g0 + 7 < NB1 || g < NB1) {      // compile-time shaped predicate
                uint4 u = w1[g];
                float a0 = bflo(u.x), a1 = bfhi(u.x), a2 = bflo(u.y), a3 = bfhi(u.y);
                float a4 = bflo(u.z), a5 = bfhi(u.z), a6 = bflo(u.w), a7 = bfhi(u.w);
#pragma unroll
                for (int b = 0; b < 4; ++b) {
                    const float* xp = xs0 + b * XS + g * 8;
                    dg[r][b] += a0 * xp[0] + a1 * xp[1] + a2 * xp[2] + a3 * xp[3]
                              + a4 * xp[4] + a5 * xp[5] + a6 * xp[6] + a7 * xp[7];
                }
            }
        }
        const uint4* __restrict__ w2 =
            reinterpret_cast<const uint4*>(whh + (size_t)(j + r * 512) * 512);
#pragma unroll
        for (int gi = 0; gi < 8; ++gi) {
            int g = gi * 8 + sub;
            uint4 u = w2[g];
            float a0 = bflo(u.x), a1 = bfhi(u.x), a2 = bflo(u.y), a3 = bfhi(u.y);
            float a4 = bflo(u.z), a5 = bfhi(u.z), a6 = bflo(u.w), a7 = bfhi(u.w);
#pragma unroll
            for (int b = 0; b < 4; ++b) {
                const float* xp = xs0 + b * XS + K1 + g * 8;
                dg[r][b] += a0 * xp[0] + a1 * xp[1] + a2 * xp[2] + a3 * xp[3]
                          + a4 * xp[4] + a5 * xp[5] + a6 * xp[6] + a7 * xp[7];
            }
        }
    }
}

// one LSTM cell (l,t) on 16 blocks x 256 thr; plain cached loads (dispatch
// boundaries provide cross-XCD coherence -- no atomics, no flags).
template <int NB1>
__device__ inline void cell_step(
    int l, int t, int bx,
    const bf16* __restrict__ wih, const bf16* __restrict__ whh,
    const float* __restrict__ bih, const float* __restrict__ bhh,
    const float* __restrict__ states,
    const float* __restrict__ featm, const float* __restrict__ feats,
    float* __restrict__ hAll, float* __restrict__ cst,
    float* __restrict__ xs)
{
    constexpr int K1 = NB1 * 8;
    constexpr int XS = K1 + 512;
    const int tid = threadIdx.x;
    const int jloc = tid >> 3;           // 0..31
    const int sub = tid & 7;             // 0..7
    const int j = bx * 32 + jloc;

    const float* hprev = (l == 0) ? nullptr
                       : hAll + ((size_t)(t + 1) * 6 + (l - 1)) * 2048;
    const float* hold  = hAll + ((size_t)t * 6 + l) * 2048;
    float* hnew        = hAll + ((size_t)(t + 1) * 6 + l) * 2048;

    if (NB1 == 72) {
        // per b: [0,512)=hprev, [512,576)=feat, [576,1088)=hold
        for (int i = tid; i < 4 * 512; i += 256) {
            int bb = i >> 9, kk = i & 511;      // float2 pair index
            float2 cv;
            int base;
            if (kk < 256) {
                cv = *reinterpret_cast<const float2*>(&hprev[bb * 512 + kk * 2]);
                base = bb * XS + kk * 2;
            } else {
                cv = *reinterpret_cast<const float2*>(&hold[bb * 512 + (kk - 256) * 2]);
                base = bb * XS + 576 + (kk - 256) * 2;
            }
            xs[base] = cv.x; xs[base + 1] = cv.y;
        }
        {
            int bb = tid >> 6, k = tid & 63;
            xs[bb * XS + 512 + k] = imgfeat(featm, feats, bb, t, k);
        }
    } else {
        // per b: [0,6)=states, [6,70)=feat, [70,72)=0, [72,584)=hold
        for (int i = tid; i < 4 * 256; i += 256) {
            int bb = i >> 8, kk = i & 255;
            float2 cv = *reinterpret_cast<const float2*>(&hold[bb * 512 + kk * 2]);
            int base = bb * XS + 72 + kk * 2;
            xs[base] = cv.x; xs[base + 1] = cv.y;
        }
        for (int i = tid; i < 4 * 72; i += 256) {
            int bb = i / 72, k = i - bb * 72;
            float v = (k < 6) ? states[(bb * 10 + t) * 6 + k]
                              : (k < 70 ? imgfeat(featm, feats, bb, t, k - 6) : 0.f);
            xs[bb * XS + k] = v;
        }
    }
    __syncthreads();

    float dg[4][4] = {{0.f, 0.f, 0.f, 0.f}, {0.f, 0.f, 0.f, 0.f},
                      {0.f, 0.f, 0.f, 0.f}, {0.f, 0.f, 0.f, 0.f}};
    cell_mm<NB1>(wih, whh, xs, j, sub, dg);

#pragma unroll
    for (int r = 0; r < 4; ++r)
#pragma unroll
        for (int b = 0; b < 4; ++b) {
            dg[r][b] += __shfl_xor(dg[r][b], 1);
            dg[r][b] += __shfl_xor(dg[r][b], 2);
            dg[r][b] += __shfl_xor(dg[r][b], 4);
        }

    if (sub == 0) {
        float b0 = bih[j] + bhh[j];
        float b1 = bih[j + 512] + bhh[j + 512];
        float b2 = bih[j + 1024] + bhh[j + 1024];
        float b3 = bih[j + 1536] + bhh[j + 1536];
#pragma unroll
        for (int b = 0; b < 4; ++b) {
            float gi = dg[0][b] + b0;
            float gf = dg[1][b] + b1;
            float gg = dg[2][b] + b2;
            float go = dg[3][b] + b3;
            float cp = cst[b * 512 + j];
            float c2 = sigmoidf_(gf) * cp + sigmoidf_(gi) * tanhf(gg);
            float h2 = sigmoidf_(go) * tanhf(c2);
            cst[b * 512 + j] = c2;
            hnew[b * 512 + j] = h2;
        }
    }
}

// ---------------- LSTM: one dispatch per anti-diagonal ----------------------
// grid = dim3(16, 7): y = layer slot (6 = out projection), x = gate block.
// Dispatch boundary = HW-optimized cross-XCD sync. R2-R7 established: every
// intra-kernel handoff protocol (acquire, relaxed, per-block flags, LLC RMW)
// costs ~20us/hop on this chip -- same as a dispatch. Dispatches are simpler.
__global__ __launch_bounds__(256) void lstm_diag2_k(
    const bf16* __restrict__ wih0p, const bf16* __restrict__ whh0b,
    const bf16* __restrict__ wihrb, const bf16* __restrict__ whhrb,
    const float* __restrict__ bih0, const float* __restrict__ bhh0,
    const float* __restrict__ bihr, const float* __restrict__ bhhr,
    const float* __restrict__ states,
    const float* __restrict__ featm, const float* __restrict__ feats,
    float* __restrict__ hAll, float* __restrict__ cAll,
    const float* __restrict__ out_w, const float* __restrict__ out_b,
    float* __restrict__ out, int d)
{
    const int l = blockIdx.y;
    const int bx = blockIdx.x;
    const int tid = threadIdx.x;
    __shared__ float xs[4 * 1088];

    if (l == 6) {                       // out projection for t = d-6
        int t = d - 6;
        if (t < 0 || t >= 10 || bx != 0) return;
        const float* h5 = hAll + ((size_t)(t + 1) * 6 + 5) * 2048;
        int p = tid >> 3, sub = tid & 7;
        if (p >= 24) return;
        int b = p / 6, a = p % 6;
        const float* wr = out_w + a * 576;
        float acc = 0.f;
        for (int k = sub; k < 256; k += 8) {
            float2 cv = *reinterpret_cast<const float2*>(&h5[b * 512 + k * 2]);
            acc += wr[k * 2] * cv.x + wr[k * 2 + 1] * cv.y;
        }
        for (int k = sub; k < 64; k += 8)
            acc += wr[512 + k] * imgfeat(featm, feats, b, t, k);
        acc += __shfl_xor(acc, 1);
        acc += __shfl_xor(acc, 2);
        acc += __shfl_xor(acc, 4);
        if (sub == 0) out[(b * 10 + t) * 6 + a] = acc + out_b[a];
        return;
    }

    const int t = d - l;
    if (t < 0 || t >= 10) return;

    float* cst = cAll + (size_t)l * 2048;
    if (l == 0) {
        cell_step<9>(0, t, bx, wih0p, whh0b, bih0, bhh0,
                     states, featm, feats, hAll, cst, xs);
    } else {
        const bf16* wih = wihrb + (size_t)(l - 1) * 2048 * 576;
        const bf16* whh = whhrb + (size_t)(l - 1) * 2048 * 512;
        const float* bih = bihr + (l - 1) * 2048;
        const float* bhh = bhhr + (l - 1) * 2048;
        cell_step<72>(l, t, bx, wih, whh, bih, bhh,
                      states, featm, feats, hAll, cst, xs);
    }
}

// ---------------- host orchestration ----------------------------------------
extern "C" void kernel_launch(void* const* d_in, const int* in_sizes, int n_in,
                              void* d_out, int out_size, void* d_ws, size_t ws_size,
                              hipStream_t stream)
{
    const float* seq_m = (const float*)d_in[0];
    const float* seq_s = (const float*)d_in[1];
    const float* states = (const float*)d_in[2];
    const float *cw[2][4], *cb[2][4];
    for (int cam = 0; cam < 2; ++cam)
        for (int j = 0; j < 4; ++j) {
            cw[cam][j] = (const float*)d_in[3 + cam * 8 + j * 2];
            cb[cam][j] = (const float*)d_in[3 + cam * 8 + j * 2 + 1];
        }
    const float* wih0  = (const float*)d_in[19];
    const float* whh0  = (const float*)d_in[20];
    const float* bih0  = (const float*)d_in[21];
    const float* bhh0  = (const float*)d_in[22];
    const float* wih_r = (const float*)d_in[23];
    const float* whh_r = (const float*)d_in[24];
    const float* bih_r = (const float*)d_in[25];
    const float* bhh_r = (const float*)d_in[26];
    const float* out_w = (const float*)d_in[27];
    const float* out_b = (const float*)d_in[28];
    float* out = (float*)d_out;

    // ---- workspace carve (256B-aligned) ----
    char* wsc = (char*)d_ws;
    auto carve = [&](size_t bytes) {
        char* p = wsc;
        wsc += (bytes + 255) & ~(size_t)255;
        return p;
    };
    float* featm = (float*)carve(40 * 32 * 4);
    float* feats = (float*)carve(40 * 32 * 4);
    float* hAll  = (float*)carve((size_t)11 * 6 * 2048 * 4);
    float* cAll  = (float*)carve((size_t)6 * 2048 * 4);
    char*  zpage = carve(8192);
    float* partial = (float*)carve((size_t)80 * 16 * 256 * 4 * 4);
    const int wtElts[4] = {3072, 18432, 73728, 18432};
    bf16* wT[2][4];
    for (int cam = 0; cam < 2; ++cam)
        for (int j = 0; j < 4; ++j) wT[cam][j] = (bf16*)carve(wtElts[j] * 2);
    bf16* wih0p = (bf16*)carve((size_t)2048 * 72 * 2);
    bf16* whh0b = (bf16*)carve((size_t)2048 * 512 * 2);
    bf16* wihrb = (bf16*)carve((size_t)5 * 2048 * 576 * 2);
    bf16* whhrb = (bf16*)carve((size_t)5 * 2048 * 512 * 2);

    size_t used = (size_t)(wsc - (char*)d_ws);
    size_t rem = ws_size > used ? ws_size - used : 0;
    int CHI = 1;
    const int cands[8] = {40, 20, 10, 8, 5, 4, 2, 1};
    for (int i = 0; i < 8; ++i) {
        size_t need = (size_t)2 * cands[i] * (128 + 64) * HWPX * 2;
        if (need <= rem) { CHI = cands[i]; break; }
    }
    bf16* bufA = (bf16*)carve((size_t)2 * CHI * HWPX * 128 * 2);
    bf16* bufB = (bf16*)carve((size_t)2 * CHI * HWPX * 64 * 2);

    hipMemsetAsync(hAll, 0, 6 * 2048 * 4, stream);       // t=-1 slot
    hipMemsetAsync(cAll, 0, 6 * 2048 * 4, stream);
    hipMemsetAsync(zpage, 0, 8192, stream);

    // ---- weight preps ----
    prep_lstm_k<<<2048, 256, 0, stream>>>(wih0, whh0, wih_r, whh_r,
                                          wih0p, whh0b, wihrb, whhrb);
    ConvW cwArg;
    for (int cam = 0; cam < 2; ++cam)
        for (int j = 0; j < 4; ++j) {
            cwArg.src[cam * 4 + j] = cw[cam][j];
            cwArg.dst[cam * 4 + j] = wT[cam][j];
        }
    prep_conv_k<<<888, 256, 0, stream>>>(cwArg);

    // ---- CNN + fused spatial softmax (both cams per dispatch) ----
    for (int c0 = 0; c0 < 40; c0 += CHI) {
        int ch = (40 - c0) < CHI ? (40 - c0) : CHI;
        conv01<<<dim3(128, 2, ch), 256, 0, stream>>>(
            seq_m, seq_s, wT[0][0], wT[1][0], cb[0][0], cb[1][0],
            wT[0][1], wT[1][1], cb[0][1], cb[1][1], bufB, c0);
        conv2r<64, 128><<<dim3(128, 2, ch), 256, 0, stream>>>(
            bufB, wT[0][2], wT[1][2], cb[0][2], cb[1][2], bufA, zpage);
        conv4_r4<<<dim3(64, 2, ch), 256, 0, stream>>>(
            bufA, wT[0][3], wT[1][3], cb[0][3], cb[1][3], partial, zpage, c0);
    }
    ssmerge_k<<<80, 256, 0, stream>>>(partial, featm, feats);

    // ---- LSTM wavefront: 16 small dispatches (112 blocks each) -------------
    for (int d = 0; d < 16; ++d) {
        lstm_diag2_k<<<dim3(16, 7), 256, 0, stream>>>(
            wih0p, whh0b, wihrb, whhrb, bih0, bhh0, bih_r, bhh_r,
            states, featm, feats, hAll, cAll, out_w, out_b, out, d);
    }
}

// Round 10
// 1074.530 us; speedup vs baseline: 1.1357x; 1.0362x over previous
//
#include <hip/hip_runtime.h>
#include <hip/hip_bf16.h>
#include <math.h>

typedef __hip_bfloat16 bf16;
typedef short bf16x8 __attribute__((ext_vector_type(8)));
typedef float f32x4 __attribute__((ext_vector_type(4)));

static constexpr int HWPX = 16384;   // 128*128

__device__ inline float sigmoidf_(float x) { return 1.0f / (1.0f + expf(-x)); }
__device__ inline float bflo(unsigned u) { return __uint_as_float(u << 16); }
__device__ inline float bfhi(unsigned u) { return __uint_as_float(u & 0xffff0000u); }
__device__ inline int swz(int x) { return (x ^ (x >> 2)) & 3; }

// async global->LDS, 16B per lane; lds base wave-uniform (lane i -> +i*16)
__device__ inline void gll16(const bf16* g, short* l) {
    __builtin_amdgcn_global_load_lds(
        (const __attribute__((address_space(1))) void*)g,
        (__attribute__((address_space(3))) void*)l, 16, 0, 0);
}

// ---------------- prep: LSTM + conv weights in ONE dispatch -----------------
struct ConvW {
    const float* src[8];
    bf16* dst[8];
};

__global__ __launch_bounds__(256) void prep_all_k(
    const float* __restrict__ wih0, const float* __restrict__ whh0,
    const float* __restrict__ wihr, const float* __restrict__ whhr,
    bf16* __restrict__ d0, bf16* __restrict__ d1,
    bf16* __restrict__ d2, bf16* __restrict__ d3, ConvW a)
{
    const size_t nA = 2048ull * 72, nB = 2048ull * 512;
    const size_t nC = 5ull * 2048 * 576, nD = 5ull * 2048 * 512;
    const size_t nLstm = nA + nB + nC + nD;
    const size_t nConv = 2 * 113664;
    const int sizes[4] = {3072, 18432, 73728, 18432};
    const int cins[4] = {3, 32, 64, 128};
    const int couts[4] = {32, 64, 128, 16};

    for (size_t i = blockIdx.x * 256ull + threadIdx.x; i < nLstm + nConv;
         i += (size_t)gridDim.x * 256) {
        if (i < nLstm) {
            if (i < nA) {
                int c = (int)(i % 72), r = (int)(i / 72);
                d0[i] = __float2bfloat16(c < 70 ? wih0[(size_t)r * 70 + c] : 0.f);
            } else if (i < nA + nB) {
                size_t k = i - nA; d1[k] = __float2bfloat16(whh0[k]);
            } else if (i < nA + nB + nC) {
                size_t k = i - nA - nB; d2[k] = __float2bfloat16(wihr[k]);
            } else {
                size_t k = i - nA - nB - nC; d3[k] = __float2bfloat16(whhr[k]);
            }
        } else {
            int ci = (int)(i - nLstm), cam = 0;
            if (ci >= 113664) { cam = 1; ci -= 113664; }
            int layer = 0;
            while (layer < 3 && ci >= sizes[layer]) { ci -= sizes[layer]; ++layer; }
            const float* w = a.src[cam * 4 + layer];
            bf16* d = a.dst[cam * 4 + layer];
            if (layer == 0) {
                // [3ky][32co][32k], k = kx*8 + c
                int k = ci & 31, co = (ci >> 5) & 31, ky = ci >> 10;
                int kx = k >> 3, c = k & 7;
                float v = (kx < 3 && c < 3) ? w[((co * 3 + c) * 3 + ky) * 3 + kx] : 0.f;
                d[ci] = __float2bfloat16(v);
            } else {
                // dst [tap][kc][q][co][8]
                int CIN = cins[layer], COUT = couts[layer], KC = CIN / 32;
                int e = ci & 7;
                int t2 = ci >> 3;
                int co = t2 % COUT;
                int t3 = t2 / COUT;
                int q = t3 & 3;
                int t4 = t3 >> 2;
                int kc = t4 % KC;
                int tap = t4 / KC;
                d[ci] = __float2bfloat16(w[((size_t)(co * CIN + kc * 32 + q * 8 + e)) * 9 + tap]);
            }
        }
    }
}

// ---------------- fused conv0+conv1: raw fp32 -> 64ch bf16 ------------------
// R10: wave = conv0 output row (balanced 30 MFMAs/wave, was 18-27);
// invalid border positions store explicit zeros (pre-zero pass removed);
// occupancy 4 -> 5 blocks/CU (29.9 KB LDS, launch_bounds (256,5)).
__global__ __launch_bounds__(256, 5) void conv01(
    const float* __restrict__ srcm, const float* __restrict__ srcs,
    const bf16* __restrict__ w0m, const bf16* __restrict__ w0s,
    const float* __restrict__ b0m, const float* __restrict__ b0s,
    const bf16* __restrict__ wTm, const bf16* __restrict__ wTs,
    const float* __restrict__ bm, const float* __restrict__ bs,
    bf16* __restrict__ out, int c0)
{
    constexpr int COUT = 64, MW = 2;          // conv1: 32 -> 64
    constexpr int SLOTS = 4 * 264;            // 4 rows x 66 px x 4 granules

    const int y0 = (blockIdx.x >> 1) * 2;
    const int x0 = (blockIdx.x & 1) * 64;
    const int cam = blockIdx.y;
    const int img = blockIdx.z;
    const int ci_ = cam * gridDim.z + img;
    const float* inImg = (cam ? srcs : srcm) + (size_t)(c0 + img) * 3 * HWPX;
    const bf16* wT0 = cam ? w0s : w0m;
    const float* bias0 = cam ? b0s : b0m;
    const bf16* wT = cam ? wTs : wTm;
    const float* bias = cam ? bs : bm;
    const int tid = threadIdx.x;
    const int wave = tid >> 6, lane = tid & 63;
    const int wrow = wave >> 1, wm = wave & 1;
    const int q = lane >> 4, n16 = lane & 15;

    __shared__ short smem[SLOTS * 8];         // conv0 out / conv1 in
    __shared__ short raw[6 * 68 * 16];        // conv0 input fragments

    // stage raw halo: rows y0-2..y0+3, px x0-2..x0+65, 3 channels
    for (int d = tid; d < 6 * 68; d += 256) {
        int x = d % 68, r = d / 68;
        int yy = y0 - 2 + r, xx = x0 - 2 + x;
        bf16 v8[8];
#pragma unroll
        for (int c = 0; c < 8; ++c) v8[c] = __float2bfloat16(0.f);
        if ((unsigned)yy < 128u && (unsigned)xx < 128u) {
            int o = yy * 128 + xx;
            v8[0] = __float2bfloat16(inImg[o]);
            v8[1] = __float2bfloat16(inImg[HWPX + o]);
            v8[2] = __float2bfloat16(inImg[2 * HWPX + o]);
        }
        *(bf16x8*)(void*)&raw[d * 16] = *(bf16x8*)(void*)v8;
        *(bf16x8*)(void*)&raw[d * 16 + 8] = (bf16x8)0;
    }
    __syncthreads();

    // conv0 MFMA: wave = row rp; xg 0..4 x coH 0..1; explicit zero stores for
    // out-of-image positions give full slot coverage (no pre-zero needed).
    {
        const int rp = wave;                   // 0..3 (global row y0-1+rp)
        const int Y = y0 - 1 + rp;
        const bool yok = (unsigned)Y < 128u;
        for (int xg = 0; xg < 5; ++xg) {
            int xt = xg * 16 + n16;
            int xts = xt < 66 ? xt : 65;       // clamp keeps LDS reads legal
#pragma unroll
            for (int coH = 0; coH < 2; ++coH) {
                f32x4 a0 = f32x4{0.f, 0.f, 0.f, 0.f};
#pragma unroll
                for (int ky = 0; ky < 3; ++ky) {
                    bf16x8 aF = *(const bf16x8*)(const void*)(wT0 +
                        ((size_t)(ky * 32 + coH * 16 + n16) * 32) + q * 8);
                    int off = (q < 3) ? ((rp + ky) * 68 + xts + q) * 16
                                      : ((rp + ky) * 68 + xts) * 16 + 8;
                    bf16x8 bF = *(const bf16x8*)(const void*)&raw[off];
                    a0 = __builtin_amdgcn_mfma_f32_16x16x32_bf16(aF, bF, a0, 0, 0, 0);
                }
                if (xt < 66) {
                    int X = x0 - 1 + xt;
                    bool ok = yok && (unsigned)X < 128u;
                    int cb0 = coH * 16 + q * 4;
                    bf16 tmp[4];
#pragma unroll
                    for (int r = 0; r < 4; ++r) {
                        float v = 0.f;
                        if (ok) {
                            v = a0[r] + bias0[cb0 + r];
                            v = v > 0.f ? v : 0.f;
                        }
                        tmp[r] = __float2bfloat16(v);
                    }
                    int g = cb0 >> 3;                       // granule 0..3
                    int sbase = (rp * 264 + xt * 4 + (g ^ swz(xt))) * 8 + (q & 1) * 4;
                    *reinterpret_cast<uint2*>(&smem[sbase]) = *reinterpret_cast<uint2*>(tmp);
                }
            }
        }
    }
    __syncthreads();

    // conv1 compute (identical to conv2r<32,64> inner loop, KC=1)
    f32x4 acc[MW][4];
#pragma unroll
    for (int mt = 0; mt < MW; ++mt)
#pragma unroll
        for (int nt = 0; nt < 4; ++nt) acc[mt][nt] = f32x4{0.f, 0.f, 0.f, 0.f};

#pragma unroll
    for (int ky = 0; ky < 3; ++ky) {
#pragma unroll
        for (int kx = 0; kx < 3; ++kx) {
            bf16x8 aF[MW];
#pragma unroll
            for (int mt = 0; mt < MW; ++mt) {
                int co = (wm * MW + mt) * 16 + n16;
                aF[mt] = *(const bf16x8*)(const void*)(wT +
                    (((size_t)(ky * 3 + kx) * 4 + q) * COUT + co) * 8);
            }
#pragma unroll
            for (int nt = 0; nt < 4; ++nt) {
                int xt = nt * 16 + n16 + kx;           // 0..65
                int slot = (wrow + ky) * 264 + xt * 4 + (q ^ swz(xt));
                bf16x8 bF = *(const bf16x8*)(const void*)&smem[slot * 8];
#pragma unroll
                for (int mt = 0; mt < MW; ++mt)
                    acc[mt][nt] = __builtin_amdgcn_mfma_f32_16x16x32_bf16(
                        aF[mt], bF, acc[mt][nt], 0, 0, 0);
            }
        }
    }

    const int y = y0 + wrow;
#pragma unroll
    for (int mt = 0; mt < MW; ++mt) {
        int co0 = (wm * MW + mt) * 16 + q * 4;
#pragma unroll
        for (int nt = 0; nt < 4; ++nt) {
            int x = x0 + nt * 16 + n16;
            bf16 tmp[4];
#pragma unroll
            for (int r = 0; r < 4; ++r) {
                float v = acc[mt][nt][r] + bias[co0 + r];
                tmp[r] = __float2bfloat16(v > 0.f ? v : 0.f);
            }
            *reinterpret_cast<uint2*>(out + ((size_t)ci_ * HWPX + y * 128 + x) * COUT + co0)
                = *reinterpret_cast<uint2*>(tmp);
        }
    }
}

// ---------------- mid convs: 2 rows x 64px per block, gll dbuf --------------
template <int CIN, int COUT>
__global__ __launch_bounds__(256, 4) void conv2r(
    const bf16* __restrict__ in, const bf16* __restrict__ wTm,
    const bf16* __restrict__ wTs, const float* __restrict__ bm,
    const float* __restrict__ bs, bf16* __restrict__ out,
    const char* __restrict__ zpage)
{
    constexpr int KC = CIN / 32;
    constexpr int NB = (KC > 1) ? 2 : 1;
    constexpr int MW = COUT / 32;       // co tiles per wave (2 co-halves)
    constexpr int SLOTS = 4 * 264;      // 4 rows x 66 x x 4 granules

    const int y0 = (blockIdx.x >> 1) * 2;
    const int x0 = (blockIdx.x & 1) * 64;
    const int cam = blockIdx.y;
    const int img = blockIdx.z;
    const int ci_ = cam * gridDim.z + img;
    const bf16* wT = cam ? wTs : wTm;
    const float* bias = cam ? bs : bm;
    const int tid = threadIdx.x;
    const int wave = tid >> 6, lane = tid & 63;
    const int wrow = wave >> 1, wm = wave & 1;
    const int q = lane >> 4, n16 = lane & 15;

    __shared__ short smem[NB][SLOTS * 8];
    const bf16* inImg = in + (size_t)ci_ * HWPX * CIN;

    const bf16* sptr[5];
#pragma unroll
    for (int it = 0; it < 5; ++it) {
        int s = it * 256 + tid;
        int r = s / 264, s2 = s - r * 264;
        int sx = s2 >> 2;
        int g = (s2 & 3) ^ swz(sx);
        int yy = y0 + r - 1, xx = x0 + sx - 1;
        bool ok = (s < SLOTS) && ((unsigned)yy < 128u) && ((unsigned)xx < 128u);
        sptr[it] = ok ? inImg + ((size_t)yy * 128 + xx) * CIN + g * 8
                      : (const bf16*)(zpage + (tid & 255) * 16);
    }
    auto stage = [&](int kc, int buf) {
#pragma unroll
        for (int it = 0; it < 5; ++it) {
            if (it * 256 + tid < SLOTS)
                gll16(sptr[it] + kc * 32, &smem[buf][it * 2048 + wave * 512]);
        }
    };

    f32x4 acc[MW][4];
#pragma unroll
    for (int mt = 0; mt < MW; ++mt)
#pragma unroll
        for (int nt = 0; nt < 4; ++nt) acc[mt][nt] = f32x4{0.f, 0.f, 0.f, 0.f};

    stage(0, 0);
    for (int kc = 0; kc < KC; ++kc) {
        __syncthreads();
        if (kc + 1 < KC) stage(kc + 1, (kc + 1) % NB);
        const short* sb = smem[kc % NB];
#pragma unroll
        for (int ky = 0; ky < 3; ++ky) {
#pragma unroll
            for (int kx = 0; kx < 3; ++kx) {
                bf16x8 aF[MW];
#pragma unroll
                for (int mt = 0; mt < MW; ++mt) {
                    int co = (wm * MW + mt) * 16 + n16;
                    aF[mt] = *(const bf16x8*)(const void*)(wT +
                        ((((size_t)(ky * 3 + kx) * KC + kc) * 4 + q) * COUT + co) * 8);
                }
#pragma unroll
                for (int nt = 0; nt < 4; ++nt) {
                    int xt = nt * 16 + n16 + kx;           // 0..65
                    int slot = (wrow + ky) * 264 + xt * 4 + (q ^ swz(xt));
                    bf16x8 bF = *(const bf16x8*)(const void*)&sb[slot * 8];
#pragma unroll
                    for (int mt = 0; mt < MW; ++mt)
                        acc[mt][nt] = __builtin_amdgcn_mfma_f32_16x16x32_bf16(
                            aF[mt], bF, acc[mt][nt], 0, 0, 0);
                }
            }
        }
    }

    const int y = y0 + wrow;
#pragma unroll
    for (int mt = 0; mt < MW; ++mt) {
        int co0 = (wm * MW + mt) * 16 + q * 4;
#pragma unroll
        for (int nt = 0; nt < 4; ++nt) {
            int x = x0 + nt * 16 + n16;
            bf16 tmp[4];
#pragma unroll
            for (int r = 0; r < 4; ++r) {
                float v = acc[mt][nt][r] + bias[co0 + r];
                tmp[r] = __float2bfloat16(v > 0.f ? v : 0.f);
            }
            *reinterpret_cast<uint2*>(out + ((size_t)ci_ * HWPX + y * 128 + x) * COUT + co0)
                = *reinterpret_cast<uint2*>(tmp);
        }
    }
}

// ---------------- conv4 (128->16): 4 rows x 64px per block ------------------
__global__ __launch_bounds__(256, 2) void conv4_r4(
    const bf16* __restrict__ in, const bf16* __restrict__ wTm,
    const bf16* __restrict__ wTs, const float* __restrict__ bm,
    const float* __restrict__ bs,
    float* __restrict__ partial,   // [gimg][16][256] x {M,S,SX,-}
    const char* __restrict__ zpage, int c0)
{
    constexpr int CIN = 128, KC = 4;
    constexpr int RR = 4;                  // output rows per block
    constexpr int SLOTS = (RR + 2) * 264;  // 6 rows x 66 px x 4 granules = 1584
    const int y0 = (blockIdx.x >> 1) * RR;
    const int xh = blockIdx.x & 1;
    const int x0 = xh * 64;
    const int cam = blockIdx.y;
    const int img = blockIdx.z;
    const int ci_ = cam * gridDim.z + img;
    const int gimg = cam * 40 + c0 + img;
    const bf16* wT = cam ? wTs : wTm;
    const float* bias = cam ? bs : bm;
    const int tid = threadIdx.x;
    const int wave = tid >> 6, lane = tid & 63;
    const int q = lane >> 4, n16 = lane & 15;

    __shared__ short smem[2][SLOTS * 8];
    __shared__ float sred[3][RR][4][16];
    const bf16* inImg = in + (size_t)ci_ * HWPX * CIN;

    const bf16* sptr[7];
#pragma unroll
    for (int it = 0; it < 7; ++it) {
        int s = it * 256 + tid;
        int r = s / 264, s2 = s - r * 264;
        int sx = s2 >> 2;
        int g = (s2 & 3) ^ swz(sx);
        int yy = y0 + r - 1, xx = x0 + sx - 1;
        bool ok = (s < SLOTS) && ((unsigned)yy < 128u) && ((unsigned)xx < 128u);
        sptr[it] = ok ? inImg + ((size_t)yy * 128 + xx) * CIN + g * 8
                      : (const bf16*)(zpage + (tid & 255) * 16);
    }
    auto stage = [&](int kc, int buf) {
#pragma unroll
        for (int it = 0; it < 7; ++it) {
            if (it * 256 + tid < SLOTS)
                gll16(sptr[it] + kc * 32, &smem[buf][it * 2048 + wave * 512]);
        }
    };

    f32x4 acc[RR];
#pragma unroll
    for (int rp = 0; rp < RR; ++rp) acc[rp] = f32x4{0.f, 0.f, 0.f, 0.f};

    stage(0, 0);
    for (int kc = 0; kc < KC; ++kc) {
        __syncthreads();
        if (kc + 1 < KC) stage(kc + 1, (kc + 1) & 1);
        const short* sb = smem[kc & 1];
#pragma unroll
        for (int ky = 0; ky < 3; ++ky) {
#pragma unroll
            for (int kx = 0; kx < 3; ++kx) {
                bf16x8 aF = *(const bf16x8*)(const void*)(wT +
                    ((((size_t)(ky * 3 + kx) * KC + kc) * 4 + q) * 16 + n16) * 8);
                int xt = wave * 16 + n16 + kx;
                int sbase = xt * 4 + (q ^ swz(xt));
#pragma unroll
                for (int rp = 0; rp < RR; ++rp) {
                    bf16x8 bF = *(const bf16x8*)(const void*)
                        &sb[((rp + ky) * 264 + sbase) * 8];
                    acc[rp] = __builtin_amdgcn_mfma_f32_16x16x32_bf16(
                        aF, bF, acc[rp], 0, 0, 0);
                }
            }
        }
    }

    // bias + relu; online partials per row over this 64px half-row
    int x = x0 + wave * 16 + n16;
    float px = -1.f + (2.f / 127.f) * x;
    float v[RR][4], M[RR][4];
#pragma unroll
    for (int rp = 0; rp < RR; ++rp)
#pragma unroll
        for (int r = 0; r < 4; ++r) {
            float t = acc[rp][r] + bias[q * 4 + r];
            v[rp][r] = t > 0.f ? t : 0.f;
            M[rp][r] = v[rp][r];
        }
#pragma unroll
    for (int rp = 0; rp < RR; ++rp)
#pragma unroll
        for (int r = 0; r < 4; ++r) {
            M[rp][r] = fmaxf(M[rp][r], __shfl_xor(M[rp][r], 1));
            M[rp][r] = fmaxf(M[rp][r], __shfl_xor(M[rp][r], 2));
            M[rp][r] = fmaxf(M[rp][r], __shfl_xor(M[rp][r], 4));
            M[rp][r] = fmaxf(M[rp][r], __shfl_xor(M[rp][r], 8));
        }
    if (n16 == 0)
#pragma unroll
        for (int rp = 0; rp < RR; ++rp)
#pragma unroll
            for (int r = 0; r < 4; ++r) sred[0][rp][wave][q * 4 + r] = M[rp][r];
    __syncthreads();
#pragma unroll
    for (int rp = 0; rp < RR; ++rp)
#pragma unroll
        for (int r = 0; r < 4; ++r) {
            M[rp][r] = fmaxf(fmaxf(sred[0][rp][0][q * 4 + r], sred[0][rp][1][q * 4 + r]),
                             fmaxf(sred[0][rp][2][q * 4 + r], sred[0][rp][3][q * 4 + r]));
        }
    float s[RR][4], sx[RR][4];
#pragma unroll
    for (int rp = 0; rp < RR; ++rp)
#pragma unroll
        for (int r = 0; r < 4; ++r) {
            float e = expf(v[rp][r] - M[rp][r]);
            s[rp][r] = e; sx[rp][r] = e * px;
            s[rp][r] += __shfl_xor(s[rp][r], 1);  sx[rp][r] += __shfl_xor(sx[rp][r], 1);
            s[rp][r] += __shfl_xor(s[rp][r], 2);  sx[rp][r] += __shfl_xor(sx[rp][r], 2);
            s[rp][r] += __shfl_xor(s[rp][r], 4);  sx[rp][r] += __shfl_xor(sx[rp][r], 4);
            s[rp][r] += __shfl_xor(s[rp][r], 8);  sx[rp][r] += __shfl_xor(sx[rp][r], 8);
        }
    __syncthreads();
    if (n16 == 0)
#pragma unroll
        for (int rp = 0; rp < RR; ++rp)
#pragma unroll
            for (int r = 0; r < 4; ++r) {
                sred[1][rp][wave][q * 4 + r] = s[rp][r];
                sred[2][rp][wave][q * 4 + r] = sx[rp][r];
            }
    __syncthreads();
    if (tid < 16 * RR) {
        int rp = tid >> 4, c = tid & 15;
        float S = sred[1][rp][0][c] + sred[1][rp][1][c] + sred[1][rp][2][c] + sred[1][rp][3][c];
        float SX = sred[2][rp][0][c] + sred[2][rp][1][c] + sred[2][rp][2][c] + sred[2][rp][3][c];
        float Mv = fmaxf(fmaxf(sred[0][rp][0][c], sred[0][rp][1][c]),
                         fmaxf(sred[0][rp][2][c], sred[0][rp][3][c]));
        float* pp = partial + (((size_t)gimg * 16 + c) * 256 + ((y0 + rp) * 2 + xh)) * 4;
        pp[0] = Mv; pp[1] = S; pp[2] = SX;
    }
}

// ---------------- merge partials -> (ex, ey), both cams ---------------------
__global__ __launch_bounds__(256) void ssmerge_k(
    const float* __restrict__ partial, float* __restrict__ featm,
    float* __restrict__ feats)
{
    const int img = blockIdx.x;          // 0..79
    const int cam = img / 40, li = img % 40;
    float* feat = cam ? feats : featm;
    const int tid = threadIdx.x;
    const int co = tid >> 4, s = tid & 15;
    const float* base = partial + ((size_t)img * 16 + co) * 256 * 4;
    float M = -1e30f, S = 0.f, SX = 0.f, SY = 0.f;
    for (int i = s; i < 256; i += 16) {
        float m = base[i * 4], sv = base[i * 4 + 1], sxv = base[i * 4 + 2];
        float py = -1.f + (2.f / 127.f) * (i >> 1);
        float Mn = fmaxf(M, m);
        float w0 = expf(M - Mn), w1 = expf(m - Mn);
        S = S * w0 + sv * w1;
        SX = SX * w0 + sxv * w1;
        SY = SY * w0 + sv * py * w1;
        M = Mn;
    }
#pragma unroll
    for (int mask = 1; mask < 16; mask <<= 1) {
        float Mo = __shfl_xor(M, mask), So = __shfl_xor(S, mask);
        float SXo = __shfl_xor(SX, mask), SYo = __shfl_xor(SY, mask);
        float Mn = fmaxf(M, Mo);
        float w0 = expf(M - Mn), w1 = expf(Mo - Mn);
        S = S * w0 + So * w1; SX = SX * w0 + SXo * w1; SY = SY * w0 + SYo * w1;
        M = Mn;
    }
    if (s == 0) {
        feat[(size_t)li * 32 + 2 * co] = SX / S;
        feat[(size_t)li * 32 + 2 * co + 1] = SY / S;
    }
}

// ---------------- LSTM helpers ----------------------------------------------
__device__ inline float imgfeat(const float* featm, const float* feats,
                                int b, int t, int k)
{
    int idx = (b * 10 + t) * 32;
    return k < 32 ? featm[idx + k] : feats[idx + k - 32];
}

// per-thread GEMV slice: 32-gate block, all 4 batches folded into the thread.
// NB1 = K1/8 (compile-time) -> fully unrolled, pipelined weight loads.
// (verified correct in rounds 5-9)
template <int NB1>
__device__ inline void cell_mm(const bf16* __restrict__ wih,
                               const bf16* __restrict__ whh,
                               const float* __restrict__ xs0,
                               int j, int sub, float (&dg)[4][4])
{
    constexpr int K1 = NB1 * 8;
    constexpr int XS = K1 + 512;
#pragma unroll
    for (int r = 0; r < 4; ++r) {
        const uint4* __restrict__ w1 =
            reinterpret_cast<const uint4*>(wih + (size_t)(j + r * 512) * K1);
#pragma unroll
        for (int g0 = 0; g0 < NB1; g0 += 8) {
            int g = g0 + sub;
            if (g0 + 7 < NB1 || g < NB1) {      // compile-time shaped predicate
                uint4 u = w1[g];
                float a0 = bflo(u.x), a1 = bfhi(u.x), a2 = bflo(u.y), a3 = bfhi(u.y);
                float a4 = bflo(u.z), a5 = bfhi(u.z), a6 = bflo(u.w), a7 = bfhi(u.w);
#pragma unroll
                for (int b = 0; b < 4; ++b) {
                    const float* xp = xs0 + b * XS + g * 8;
                    dg[r][b] += a0 * xp[0] + a1 * xp[1] + a2 * xp[2] + a3 * xp[3]
                              + a4 * xp[4] + a5 * xp[5] + a6 * xp[6] + a7 * xp[7];
                }
            }
        }
        const uint4* __restrict__ w2 =
            reinterpret_cast<const uint4*>(whh + (size_t)(j + r * 512) * 512);
#pragma unroll
        for (int gi = 0; gi < 8; ++gi) {
            int g = gi * 8 + sub;
            uint4 u = w2[g];
            float a0 = bflo(u.x), a1 = bfhi(u.x), a2 = bflo(u.y), a3 = bfhi(u.y);
            float a4 = bflo(u.z), a5 = bfhi(u.z), a6 = bflo(u.w), a7 = bfhi(u.w);
#pragma unroll
            for (int b = 0; b < 4; ++b) {
                const float* xp = xs0 + b * XS + K1 + g * 8;
                dg[r][b] += a0 * xp[0] + a1 * xp[1] + a2 * xp[2] + a3 * xp[3]
                          + a4 * xp[4] + a5 * xp[5] + a6 * xp[6] + a7 * xp[7];
            }
        }
    }
}

// one LSTM cell (l,t) on 16 blocks x 256 thr; plain cached loads (dispatch
// boundaries provide cross-XCD coherence -- no atomics, no flags).
template <int NB1>
__device__ inline void cell_step(
    int l, int t, int bx,
    const bf16* __restrict__ wih, const bf16* __restrict__ whh,
    const float* __restrict__ bih, const float* __restrict__ bhh,
    const float* __restrict__ states,
    const float* __restrict__ featm, const float* __restrict__ feats,
    float* __restrict__ hAll, float* __restrict__ cst,
    float* __restrict__ xs)
{
    constexpr int K1 = NB1 * 8;
    constexpr int XS = K1 + 512;
    const int tid = threadIdx.x;
    const int jloc = tid >> 3;           // 0..31
    const int sub = tid & 7;             // 0..7
    const int j = bx * 32 + jloc;

    const float* hprev = (l == 0) ? nullptr
                       : hAll + ((size_t)(t + 1) * 6 + (l - 1)) * 2048;
    const float* hold  = hAll + ((size_t)t * 6 + l) * 2048;
    float* hnew        = hAll + ((size_t)(t + 1) * 6 + l) * 2048;

    if (NB1 == 72) {
        // per b: [0,512)=hprev, [512,576)=feat, [576,1088)=hold
        for (int i = tid; i < 4 * 512; i += 256) {
            int bb = i >> 9, kk = i & 511;      // float2 pair index
            float2 cv;
            int base;
            if (kk < 256) {
                cv = *reinterpret_cast<const float2*>(&hprev[bb * 512 + kk * 2]);
                base = bb * XS + kk * 2;
            } else {
                cv = *reinterpret_cast<const float2*>(&hold[bb * 512 + (kk - 256) * 2]);
                base = bb * XS + 576 + (kk - 256) * 2;
            }
            xs[base] = cv.x; xs[base + 1] = cv.y;
        }
        {
            int bb = tid >> 6, k = tid & 63;
            xs[bb * XS + 512 + k] = imgfeat(featm, feats, bb, t, k);
        }
    } else {
        // per b: [0,6)=states, [6,70)=feat, [70,72)=0, [72,584)=hold
        for (int i = tid; i < 4 * 256; i += 256) {
            int bb = i >> 8, kk = i & 255;
            float2 cv = *reinterpret_cast<const float2*>(&hold[bb * 512 + kk * 2]);
            int base = bb * XS + 72 + kk * 2;
            xs[base] = cv.x; xs[base + 1] = cv.y;
        }
        for (int i = tid; i < 4 * 72; i += 256) {
            int bb = i / 72, k = i - bb * 72;
            float v = (k < 6) ? states[(bb * 10 + t) * 6 + k]
                              : (k < 70 ? imgfeat(featm, feats, bb, t, k - 6) : 0.f);
            xs[bb * XS + k] = v;
        }
    }
    __syncthreads();

    float dg[4][4] = {{0.f, 0.f, 0.f, 0.f}, {0.f, 0.f, 0.f, 0.f},
                      {0.f, 0.f, 0.f, 0.f}, {0.f, 0.f, 0.f, 0.f}};
    cell_mm<NB1>(wih, whh, xs, j, sub, dg);

#pragma unroll
    for (int r = 0; r < 4; ++r)
#pragma unroll
        for (int b = 0; b < 4; ++b) {
            dg[r][b] += __shfl_xor(dg[r][b], 1);
            dg[r][b] += __shfl_xor(dg[r][b], 2);
            dg[r][b] += __shfl_xor(dg[r][b], 4);
        }

    if (sub == 0) {
        float b0 = bih[j] + bhh[j];
        float b1 = bih[j + 512] + bhh[j + 512];
        float b2 = bih[j + 1024] + bhh[j + 1024];
        float b3 = bih[j + 1536] + bhh[j + 1536];
#pragma unroll
        for (int b = 0; b < 4; ++b) {
            float gi = dg[0][b] + b0;
            float gf = dg[1][b] + b1;
            float gg = dg[2][b] + b2;
            float go = dg[3][b] + b3;
            float cp = cst[b * 512 + j];
            float c2 = sigmoidf_(gf) * cp + sigmoidf_(gi) * tanhf(gg);
            float h2 = sigmoidf_(go) * tanhf(c2);
            cst[b * 512 + j] = c2;
            hnew[b * 512 + j] = h2;
        }
    }
}

// ---------------- LSTM: one dispatch per anti-diagonal ----------------------
// grid = dim3(16, 7): y = layer slot (6 = out projection), x = gate block.
// Dispatch boundary = HW-optimized cross-XCD sync. R2-R7 established: every
// intra-kernel handoff protocol (acquire, relaxed, per-block flags, LLC RMW)
// costs ~20us/hop on this chip -- same as a dispatch. Dispatches are simpler.
__global__ __launch_bounds__(256) void lstm_diag2_k(
    const bf16* __restrict__ wih0p, const bf16* __restrict__ whh0b,
    const bf16* __restrict__ wihrb, const bf16* __restrict__ whhrb,
    const float* __restrict__ bih0, const float* __restrict__ bhh0,
    const float* __restrict__ bihr, const float* __restrict__ bhhr,
    const float* __restrict__ states,
    const float* __restrict__ featm, const float* __restrict__ feats,
    float* __restrict__ hAll, float* __restrict__ cAll,
    const float* __restrict__ out_w, const float* __restrict__ out_b,
    float* __restrict__ out, int d)
{
    const int l = blockIdx.y;
    const int bx = blockIdx.x;
    const int tid = threadIdx.x;
    __shared__ float xs[4 * 1088];

    if (l == 6) {                       // out projection for t = d-6
        int t = d - 6;
        if (t < 0 || t >= 10 || bx != 0) return;
        const float* h5 = hAll + ((size_t)(t + 1) * 6 + 5) * 2048;
        int p = tid >> 3, sub = tid & 7;
        if (p >= 24) return;
        int b = p / 6, a = p % 6;
        const float* wr = out_w + a * 576;
        float acc = 0.f;
        for (int k = sub; k < 256; k += 8) {
            float2 cv = *reinterpret_cast<const float2*>(&h5[b * 512 + k * 2]);
            acc += wr[k * 2] * cv.x + wr[k * 2 + 1] * cv.y;
        }
        for (int k = sub; k < 64; k += 8)
            acc += wr[512 + k] * imgfeat(featm, feats, b, t, k);
        acc += __shfl_xor(acc, 1);
        acc += __shfl_xor(acc, 2);
        acc += __shfl_xor(acc, 4);
        if (sub == 0) out[(b * 10 + t) * 6 + a] = acc + out_b[a];
        return;
    }

    const int t = d - l;
    if (t < 0 || t >= 10) return;

    float* cst = cAll + (size_t)l * 2048;
    if (l == 0) {
        cell_step<9>(0, t, bx, wih0p, whh0b, bih0, bhh0,
                     states, featm, feats, hAll, cst, xs);
    } else {
        const bf16* wih = wihrb + (size_t)(l - 1) * 2048 * 576;
        const bf16* whh = whhrb + (size_t)(l - 1) * 2048 * 512;
        const float* bih = bihr + (l - 1) * 2048;
        const float* bhh = bhhr + (l - 1) * 2048;
        cell_step<72>(l, t, bx, wih, whh, bih, bhh,
                      states, featm, feats, hAll, cst, xs);
    }
}

// ---------------- host orchestration ----------------------------------------
extern "C" void kernel_launch(void* const* d_in, const int* in_sizes, int n_in,
                              void* d_out, int out_size, void* d_ws, size_t ws_size,
                              hipStream_t stream)
{
    const float* seq_m = (const float*)d_in[0];
    const float* seq_s = (const float*)d_in[1];
    const float* states = (const float*)d_in[2];
    const float *cw[2][4], *cb[2][4];
    for (int cam = 0; cam < 2; ++cam)
        for (int j = 0; j < 4; ++j) {
            cw[cam][j] = (const float*)d_in[3 + cam * 8 + j * 2];
            cb[cam][j] = (const float*)d_in[3 + cam * 8 + j * 2 + 1];
        }
    const float* wih0  = (const float*)d_in[19];
    const float* whh0  = (const float*)d_in[20];
    const float* bih0  = (const float*)d_in[21];
    const float* bhh0  = (const float*)d_in[22];
    const float* wih_r = (const float*)d_in[23];
    const float* whh_r = (const float*)d_in[24];
    const float* bih_r = (const float*)d_in[25];
    const float* bhh_r = (const float*)d_in[26];
    const float* out_w = (const float*)d_in[27];
    const float* out_b = (const float*)d_in[28];
    float* out = (float*)d_out;

    // ---- workspace carve (256B-aligned) ----
    // NOTE: cAll, zpage, hAll are carved ADJACENT so one memset covers
    // cAll (48KB) + zpage (8KB) + hAll's t=-1 slot (48KB) = 104KB.
    char* wsc = (char*)d_ws;
    auto carve = [&](size_t bytes) {
        char* p = wsc;
        wsc += (bytes + 255) & ~(size_t)255;
        return p;
    };
    float* featm = (float*)carve(40 * 32 * 4);
    float* feats = (float*)carve(40 * 32 * 4);
    float* cAll  = (float*)carve((size_t)6 * 2048 * 4);       // 49152 B
    char*  zpage = carve(8192);                               // 8192 B
    float* hAll  = (float*)carve((size_t)11 * 6 * 2048 * 4);  // t=-1 slot first
    float* partial = (float*)carve((size_t)80 * 16 * 256 * 4 * 4);
    const int wtElts[4] = {3072, 18432, 73728, 18432};
    bf16* wT[2][4];
    for (int cam = 0; cam < 2; ++cam)
        for (int j = 0; j < 4; ++j) wT[cam][j] = (bf16*)carve(wtElts[j] * 2);
    bf16* wih0p = (bf16*)carve((size_t)2048 * 72 * 2);
    bf16* whh0b = (bf16*)carve((size_t)2048 * 512 * 2);
    bf16* wihrb = (bf16*)carve((size_t)5 * 2048 * 576 * 2);
    bf16* whhrb = (bf16*)carve((size_t)5 * 2048 * 512 * 2);

    size_t used = (size_t)(wsc - (char*)d_ws);
    size_t rem = ws_size > used ? ws_size - used : 0;
    int CHI = 1;
    const int cands[8] = {40, 20, 10, 8, 5, 4, 2, 1};
    for (int i = 0; i < 8; ++i) {
        size_t need = (size_t)2 * cands[i] * (128 + 64) * HWPX * 2;
        if (need <= rem) { CHI = cands[i]; break; }
    }
    bf16* bufA = (bf16*)carve((size_t)2 * CHI * HWPX * 128 * 2);
    bf16* bufB = (bf16*)carve((size_t)2 * CHI * HWPX * 64 * 2);

    // single memset: cAll + zpage + hAll[t=-1]
    hipMemsetAsync(cAll, 0, 49152 + 8192 + 49152, stream);

    // ---- weight prep (single dispatch) ----
    ConvW cwArg;
    for (int cam = 0; cam < 2; ++cam)
        for (int j = 0; j < 4; ++j) {
            cwArg.src[cam * 4 + j] = cw[cam][j];
            cwArg.dst[cam * 4 + j] = wT[cam][j];
        }
    prep_all_k<<<2048, 256, 0, stream>>>(wih0, whh0, wih_r, whh_r,
                                         wih0p, whh0b, wihrb, whhrb, cwArg);

    // ---- CNN + fused spatial softmax (both cams per dispatch) ----
    for (int c0 = 0; c0 < 40; c0 += CHI) {
        int ch = (40 - c0) < CHI ? (40 - c0) : CHI;
        conv01<<<dim3(128, 2, ch), 256, 0, stream>>>(
            seq_m, seq_s, wT[0][0], wT[1][0], cb[0][0], cb[1][0],
            wT[0][1], wT[1][1], cb[0][1], cb[1][1], bufB, c0);
        conv2r<64, 128><<<dim3(128, 2, ch), 256, 0, stream>>>(
            bufB, wT[0][2], wT[1][2], cb[0][2], cb[1][2], bufA, zpage);
        conv4_r4<<<dim3(64, 2, ch), 256, 0, stream>>>(
            bufA, wT[0][3], wT[1][3], cb[0][3], cb[1][3], partial, zpage, c0);
    }
    ssmerge_k<<<80, 256, 0, stream>>>(partial, featm, feats);

    // ---- LSTM wavefront: 16 small dispatches (112 blocks each) -------------
    for (int d = 0; d < 16; ++d) {
        lstm_diag2_k<<<dim3(16, 7), 256, 0, stream>>>(
            wih0p, whh0b, wihrb, whhrb, bih0, bhh0, bih_r, bhh_r,
            states, featm, feats, hAll, cAll, out_w, out_b, out, d);
    }
}